// Round 17
// baseline (582.622 us; speedup 1.0000x reference)
//
#include <hip/hip_runtime.h>
#include <hip/hip_bf16.h>

typedef __bf16 bf16_t;
typedef bf16_t bf16x8 __attribute__((ext_vector_type(8)));
typedef bf16_t bf16x4 __attribute__((ext_vector_type(4)));
typedef float f32x4 __attribute__((ext_vector_type(4)));

#define DIN 1024
#define DH 1024
#define DMOE 4096
#define NEXP 8
#define NTOK 4096

__device__ __forceinline__ void gload_lds16(const bf16_t* g, bf16_t* l) {
  __builtin_amdgcn_global_load_lds(
      (const __attribute__((address_space(1))) void*)g,
      (__attribute__((address_space(3))) void*)l, 16, 0, 0);
}

// ---------------- unified prep: 4 weight transposes + x cvt, one launch ----------
// z in [0,256) WtIn, [256,8448) W1, [8448,16640) W2, [16640,16896) WtOut,
// [16896,20992) x->bf16 linear cvt.
__global__ void k_transpose_all(const float* __restrict__ W_in, const float* __restrict__ W1,
                                const float* __restrict__ W2, const float* __restrict__ W_out,
                                const float* __restrict__ x,
                                bf16_t* __restrict__ WtIn, bf16_t* __restrict__ Wt1,
                                bf16_t* __restrict__ Wt2, bf16_t* __restrict__ WtOut,
                                bf16_t* __restrict__ xbf) {
  const int z = blockIdx.x;
  if (z >= 16896) {
    const int i = (z - 16896) * 256 + threadIdx.x;
    const float4 v = *(const float4*)(x + (size_t)i * 4);
    bf16x4 o;
    o.x = (bf16_t)v.x; o.y = (bf16_t)v.y; o.z = (bf16_t)v.z; o.w = (bf16_t)v.w;
    *(bf16x4*)(xbf + (size_t)i * 4) = o;
    return;
  }
  const float* s; bf16_t* d; int R, C, tx, ty;
  if (z < 256) {
    s = W_in; d = WtIn; R = DIN; C = DH; tx = z & 15; ty = z >> 4;
  } else if (z < 8448) {
    const int l = z - 256, e = l >> 10, t = l & 1023;
    s = W1 + (size_t)e * DH * DMOE; d = Wt1 + (size_t)e * DH * DMOE;
    R = DH; C = DMOE; tx = t & 63; ty = t >> 6;
  } else if (z < 16640) {
    const int l = z - 8448, e = l >> 10, t = l & 1023;
    s = W2 + (size_t)e * DMOE * DH; d = Wt2 + (size_t)e * DMOE * DH;
    R = DMOE; C = DH; tx = t & 15; ty = t >> 4;
  } else {
    const int t = z - 16640;
    s = W_out; d = WtOut; R = DH; C = DH; tx = t & 15; ty = t >> 4;
  }
  __shared__ float tile[64][65];
  const int c0 = tx * 64, r0 = ty * 64;
  const int t = threadIdx.x;
  const int rr = t >> 4;
  const int cc = (t & 15) << 2;
#pragma unroll
  for (int i = 0; i < 64; i += 16) {
    const float4 v = *(const float4*)&s[(size_t)(r0 + rr + i) * C + c0 + cc];
    tile[rr + i][cc + 0] = v.x;
    tile[rr + i][cc + 1] = v.y;
    tile[rr + i][cc + 2] = v.z;
    tile[rr + i][cc + 3] = v.w;
  }
  __syncthreads();
  const int orr = (t & 7) * 8;
  const int oc = t >> 3;
#pragma unroll
  for (int i = 0; i < 64; i += 32) {
    bf16x8 o;
#pragma unroll
    for (int j = 0; j < 8; ++j) o[j] = (bf16_t)tile[orr + j][oc + i];
    *(bf16x8*)&d[(size_t)(c0 + oc + i) * R + r0 + orr] = o;
  }
}

// G[d][e] = sum_k W_in[d][k] * W_gate[k][e]  (fp64); row d==DH computes c[e] from b_in.
__global__ void k_gate_prep(const float* __restrict__ Win, const float* __restrict__ Wgate,
                            const float* __restrict__ b_in, const float* __restrict__ b_gate,
                            double* __restrict__ G, double* __restrict__ cvec,
                            int* __restrict__ cnt) {
  if (blockIdx.x == 0 && threadIdx.x < 8) cnt[threadIdx.x] = 0;
  const int lane = threadIdx.x & 63;
  const int wave = (blockIdx.x * blockDim.x + threadIdx.x) >> 6;
  const int nw = (gridDim.x * blockDim.x) >> 6;
  for (int d = wave; d <= DIN; d += nw) {
    const float* row = (d < DIN) ? (Win + (size_t)d * DH) : b_in;
    double acc[8] = {0, 0, 0, 0, 0, 0, 0, 0};
    for (int k = lane; k < DH; k += 64) {
      const double xv = (double)row[k];
      const float* g = Wgate + (size_t)k * NEXP;
#pragma unroll
      for (int ee = 0; ee < 8; ++ee) acc[ee] += xv * (double)g[ee];
    }
#pragma unroll
    for (int ee = 0; ee < 8; ++ee) {
      double a = acc[ee];
      for (int o = 32; o > 0; o >>= 1) a += __shfl_down(a, o);
      acc[ee] = a;
    }
    if (lane == 0) {
      if (d < DIN) {
#pragma unroll
        for (int ee = 0; ee < 8; ++ee) G[(size_t)d * 8 + ee] = acc[ee];
      } else {
#pragma unroll
        for (int ee = 0; ee < 8; ++ee) cvec[ee] = acc[ee] + (double)b_gate[ee];
      }
    }
  }
}

// per token: fp64 logits via fused G, softmax, top-2, scatter into expert lists
__global__ void k_gating(const float* __restrict__ x, const double* __restrict__ G,
                         const double* __restrict__ cvec, int* __restrict__ cnt,
                         int* __restrict__ list, float* __restrict__ wlist) {
  const int lane = threadIdx.x & 63;
  const int t = blockIdx.x * (blockDim.x >> 6) + (threadIdx.x >> 6);
  if (t >= NTOK) return;
  const float* xr = x + (size_t)t * DIN;
  double acc[8] = {0, 0, 0, 0, 0, 0, 0, 0};
  for (int d = lane; d < DIN; d += 64) {
    const double xv = (double)xr[d];
    const double* g = G + (size_t)d * 8;
#pragma unroll
    for (int ee = 0; ee < 8; ++ee) acc[ee] += xv * g[ee];
  }
#pragma unroll
  for (int ee = 0; ee < 8; ++ee) {
    double a = acc[ee];
    for (int o = 32; o > 0; o >>= 1) a += __shfl_down(a, o);
    acc[ee] = a;
  }
  if (lane == 0) {
    double l[8];
#pragma unroll
    for (int ee = 0; ee < 8; ++ee) l[ee] = acc[ee] + cvec[ee];
    double m = l[0];
#pragma unroll
    for (int ee = 1; ee < 8; ++ee) m = fmax(m, l[ee]);
    double p[8];
#pragma unroll
    for (int ee = 0; ee < 8; ++ee) p[ee] = exp(l[ee] - m);
    int i1 = 0;
#pragma unroll
    for (int ee = 1; ee < 8; ++ee)
      if (p[ee] > p[i1]) i1 = ee;
    int i2 = (i1 == 0) ? 1 : 0;
#pragma unroll
    for (int ee = 0; ee < 8; ++ee)
      if (ee != i1 && p[ee] > p[i2]) i2 = ee;
    const double s2 = p[i1] + p[i2];
    const float w1 = (float)(p[i1] / s2);
    const float w2 = (float)(p[i2] / s2);
    int lp = atomicAdd(&cnt[i1], 1);
    list[i1 * NTOK + lp] = t * 2;
    wlist[i1 * NTOK + lp] = w1;
    lp = atomicAdd(&cnt[i2], 1);
    list[i2 * NTOK + lp] = t * 2 + 1;
    wlist[i2 * NTOK + lp] = w2;
  }
}

__global__ void k_scan(const int* __restrict__ cnt, int* __restrict__ offs) {
  if (threadIdx.x == 0) {
    int s = 0;
    for (int e = 0; e < NEXP; ++e) { offs[e] = s; s += cnt[e]; }
    offs[NEXP] = s;
  }
}

// moe_bf16[t] = bf16(sum of 4 fp32 partials: 2 slots x 2 K-halves)
__global__ void k_combine4(const float* __restrict__ e32, bf16_t* __restrict__ moebf) {
  const int i = blockIdx.x * blockDim.x + threadIdx.x;
  const int t = i >> 8;
  const int q = (i & 255) * 4;
  const float4 a = *(const float4*)(e32 + ((size_t)t * 2) * DH + q);
  const float4 b = *(const float4*)(e32 + ((size_t)t * 2 + 1) * DH + q);
  const float4 c = *(const float4*)(e32 + ((size_t)(2 * NTOK + t * 2)) * DH + q);
  const float4 d = *(const float4*)(e32 + ((size_t)(2 * NTOK + t * 2 + 1)) * DH + q);
  bf16x4 o;
  o.x = (bf16_t)(a.x + b.x + c.x + d.x);
  o.y = (bf16_t)(a.y + b.y + c.y + d.y);
  o.z = (bf16_t)(a.z + b.z + c.z + d.z);
  o.w = (bf16_t)(a.w + b.w + c.w + d.w);
  *(bf16x4*)(moebf + (size_t)t * DH + q) = o;
}

// ---------------- 128x128 BK=32 plain GEMM, 4 waves (R10 structure) ----------
template <int OUT_F32>
__global__ __launch_bounds__(256, 3) void k_gemm_plain(
    const bf16_t* __restrict__ A, const bf16_t* __restrict__ B,
    const float* __restrict__ bias, void* __restrict__ Cbase,
    int M, int N, int K) {
  const int mblk = blockIdx.y, nblk = blockIdx.x;

  __shared__ bf16_t As[3][128 * 32];
  __shared__ bf16_t Bs[3][128 * 32];

  const int tid = threadIdx.x;
  const int lane = tid & 63;
  const int wid = tid >> 6;
  const int wr = wid >> 1, wc = wid & 1;

  const int srow0 = wid * 32 + (lane >> 2);
  const int srow1 = srow0 + 16;
  const int skcol = ((lane & 3) ^ ((lane >> 3) & 3)) * 8;

  const bf16_t* aptr0 = A + (size_t)(mblk * 128 + srow0) * K + skcol;
  const bf16_t* aptr1 = A + (size_t)(mblk * 128 + srow1) * K + skcol;
  const bf16_t* bptr0 = B + (size_t)(nblk * 128 + srow0) * K + skcol;
  const bf16_t* bptr1 = B + (size_t)(nblk * 128 + srow1) * K + skcol;

  const int ldsOfsA0 = (wid * 32) * 32;
  const int ldsOfsA1 = (wid * 32 + 16) * 32;

  f32x4 acc[4][4] = {};
  const int nkt = K >> 5;

  auto stage = [&](int buf, int kt) {
    const size_t ko = (size_t)kt * 32;
    gload_lds16(aptr0 + ko, &As[buf][ldsOfsA0]);
    gload_lds16(aptr1 + ko, &As[buf][ldsOfsA1]);
    gload_lds16(bptr0 + ko, &Bs[buf][ldsOfsA0]);
    gload_lds16(bptr1 + ko, &Bs[buf][ldsOfsA1]);
  };

  stage(0, 0);
  if (nkt > 1) stage(1, 1);

  const int fr = lane & 15;
  const int s0 = (((lane >> 4) ^ ((fr >> 1) & 3)) << 3);

  int cur = 0;
  for (int kt = 0; kt < nkt; ++kt) {
    int nxt = cur + 2;
    if (nxt >= 3) nxt -= 3;
    if (kt + 2 < nkt) {
      stage(nxt, kt + 2);
      asm volatile("s_waitcnt vmcnt(8)" ::: "memory");
    } else if (kt + 1 < nkt) {
      asm volatile("s_waitcnt vmcnt(4)" ::: "memory");
    } else {
      asm volatile("s_waitcnt vmcnt(0)" ::: "memory");
    }
    __builtin_amdgcn_s_barrier();

    bf16x8 af[4], bfr[4];
#pragma unroll
    for (int m = 0; m < 4; ++m)
      af[m] = *(const bf16x8*)&As[cur][(wr * 64 + m * 16 + fr) * 32 + s0];
#pragma unroll
    for (int n = 0; n < 4; ++n)
      bfr[n] = *(const bf16x8*)&Bs[cur][(wc * 64 + n * 16 + fr) * 32 + s0];
#pragma unroll
    for (int m = 0; m < 4; ++m)
#pragma unroll
      for (int n = 0; n < 4; ++n)
        acc[m][n] = __builtin_amdgcn_mfma_f32_16x16x32_bf16(af[m], bfr[n], acc[m][n], 0, 0, 0);

    __builtin_amdgcn_s_barrier();
    cur += 1;
    if (cur >= 3) cur -= 3;
  }

  const int colBase = nblk * 128 + wc * 64 + (lane & 15);
  const int rowBase = mblk * 128 + wr * 64 + ((lane >> 4) << 2);
#pragma unroll
  for (int n = 0; n < 4; ++n) {
    const int c = colBase + n * 16;
    const float bv = bias[c];
#pragma unroll
    for (int m = 0; m < 4; ++m) {
#pragma unroll
      for (int j = 0; j < 4; ++j) {
        const int r = rowBase + m * 16 + j;
        const float v = acc[m][n][j] + bv;
        if constexpr (OUT_F32 == 0) {
          ((bf16_t*)Cbase)[(size_t)r * N + c] = (bf16_t)v;
        } else {
          ((float*)Cbase)[(size_t)r * N + c] = v;
        }
      }
    }
  }
}

// ---------------- 256x128 BK=32 expert GEMM1, 8 waves (R15-proven) ------
// A rows gathered via list (token = entry>>1); relu; bf16 out at rowOff+r.
__global__ __launch_bounds__(512, 4) void k_gemm1(
    const bf16_t* __restrict__ Abase, const bf16_t* __restrict__ Bbase,
    const float* __restrict__ biasBase, bf16_t* __restrict__ Cbase,
    int N, int K,
    const int* __restrict__ cnt, const int* __restrict__ offs,
    const int* __restrict__ listBase) {
  const int e = blockIdx.z;
  const int mblk = blockIdx.y, nblk = blockIdx.x;
  const int Mloc = cnt[e];
  if (mblk * 256 >= Mloc) return;
  const bf16_t* B = Bbase + (size_t)e * N * K;
  const float* bias = biasBase + (size_t)e * N;
  const int* myList = listBase + e * NTOK;
  const int rowOff = offs[e];

  __shared__ bf16_t As[3][256 * 32];
  __shared__ bf16_t Bs[3][128 * 32];

  const int tid = threadIdx.x;
  const int lane = tid & 63;
  const int wid = tid >> 6;
  const int wr = wid >> 1, wc = wid & 1;

  const int subr = lane >> 2;
  const int skcol = ((lane & 3) ^ ((lane >> 3) & 3)) * 8;

  uint32_t aofs[2];
#pragma unroll
  for (int l = 0; l < 2; ++l) {
    int ar = mblk * 256 + (wid * 2 + l) * 16 + subr;
    if (ar > Mloc - 1) ar = Mloc - 1;
    aofs[l] = (uint32_t)(myList[ar] >> 1) * (uint32_t)K + skcol;
  }
  const uint32_t bofs = (uint32_t)(nblk * 128 + wid * 16 + subr) * (uint32_t)K + skcol;

  f32x4 acc[4][4] = {};
  const int nkt = K >> 5;

  auto stage = [&](int buf, int kt) {
    const uint32_t ko = (uint32_t)kt * 32;
    gload_lds16(Abase + aofs[0] + ko, &As[buf][(wid * 2 + 0) * 512]);
    gload_lds16(Abase + aofs[1] + ko, &As[buf][(wid * 2 + 1) * 512]);
    gload_lds16(B + bofs + ko, &Bs[buf][wid * 512]);
  };

  stage(0, 0);
  if (nkt > 1) stage(1, 1);

  const int fr = lane & 15;
  const int s0 = (((lane >> 4) ^ ((fr >> 1) & 3)) << 3);

  int cur = 0;
  for (int kt = 0; kt < nkt; ++kt) {
    int nxt = cur + 2;
    if (nxt >= 3) nxt -= 3;
    if (kt + 2 < nkt) {
      stage(nxt, kt + 2);
      asm volatile("s_waitcnt vmcnt(6)" ::: "memory");
    } else if (kt + 1 < nkt) {
      asm volatile("s_waitcnt vmcnt(3)" ::: "memory");
    } else {
      asm volatile("s_waitcnt vmcnt(0)" ::: "memory");
    }
    __builtin_amdgcn_s_barrier();

    bf16x8 af[4], bfr[4];
#pragma unroll
    for (int m = 0; m < 4; ++m)
      af[m] = *(const bf16x8*)&As[cur][(wr * 64 + m * 16 + fr) * 32 + s0];
#pragma unroll
    for (int n = 0; n < 4; ++n)
      bfr[n] = *(const bf16x8*)&Bs[cur][(wc * 64 + n * 16 + fr) * 32 + s0];
#pragma unroll
    for (int m = 0; m < 4; ++m)
#pragma unroll
      for (int n = 0; n < 4; ++n)
        acc[m][n] = __builtin_amdgcn_mfma_f32_16x16x32_bf16(af[m], bfr[n], acc[m][n], 0, 0, 0);

    __builtin_amdgcn_s_barrier();
    cur += 1;
    if (cur >= 3) cur -= 3;
  }

  const int colBase = nblk * 128 + wc * 64 + (lane & 15);
  const int rowBase = mblk * 256 + wr * 64 + ((lane >> 4) << 2);
#pragma unroll
  for (int n = 0; n < 4; ++n) {
    const int c = colBase + n * 16;
    const float bv = bias[c];
#pragma unroll
    for (int m = 0; m < 4; ++m) {
#pragma unroll
      for (int j = 0; j < 4; ++j) {
        const int r = rowBase + m * 16 + j;
        if (r < Mloc) {
          Cbase[(size_t)(rowOff + r) * N + c] = (bf16_t)fmaxf(acc[m][n][j] + bv, 0.0f);
        }
      }
    }
  }
}

// ---------------- 256x128 BK=32 split-K=2 expert GEMM2, 8 waves ------------------
// z = e*2+half; each block computes K-half [half*K/2, (half+1)*K/2).  A contiguous
// (mid + offs[e]).  fp32 partial out: e32[half*2N + entry][c] = (acc + bias?half0)*w.
// Staged bytes unchanged vs BM=256 full-K; active blocks 2x (512 = 2/CU, full).
__global__ __launch_bounds__(512, 4) void k_gemm2s(
    const bf16_t* __restrict__ Abase, const bf16_t* __restrict__ Bbase,
    const float* __restrict__ biasBase, float* __restrict__ Cbase,
    int N, int K,
    const int* __restrict__ cnt, const int* __restrict__ offs,
    const int* __restrict__ listBase, const float* __restrict__ wlistBase) {
  const int e = blockIdx.z >> 1;
  const int half = blockIdx.z & 1;
  const int mblk = blockIdx.y, nblk = blockIdx.x;
  const int Mloc = cnt[e];
  if (mblk * 256 >= Mloc) return;
  const bf16_t* B = Bbase + (size_t)e * N * K;
  const float* bias = biasBase + (size_t)e * N;
  const int* myList = listBase + e * NTOK;
  const float* myW = wlistBase + e * NTOK;
  const bf16_t* A = Abase + (size_t)offs[e] * K;

  __shared__ bf16_t As[3][256 * 32];
  __shared__ bf16_t Bs[3][128 * 32];

  const int tid = threadIdx.x;
  const int lane = tid & 63;
  const int wid = tid >> 6;
  const int wr = wid >> 1, wc = wid & 1;

  const int subr = lane >> 2;
  const int skcol = ((lane & 3) ^ ((lane >> 3) & 3)) * 8;

  uint32_t aofs[2];
#pragma unroll
  for (int l = 0; l < 2; ++l) {
    int ar = mblk * 256 + (wid * 2 + l) * 16 + subr;
    if (ar > Mloc - 1) ar = Mloc - 1;
    aofs[l] = (uint32_t)ar * (uint32_t)K + skcol;
  }
  const uint32_t bofs = (uint32_t)(nblk * 128 + wid * 16 + subr) * (uint32_t)K + skcol;
  const uint32_t kbase = (uint32_t)half * (uint32_t)(K >> 1);

  f32x4 acc[4][4] = {};
  const int nkt = K >> 6;  // half-K in BK=32 tiles

  auto stage = [&](int buf, int kt) {
    const uint32_t ko = kbase + (uint32_t)kt * 32;
    gload_lds16(A + aofs[0] + ko, &As[buf][(wid * 2 + 0) * 512]);
    gload_lds16(A + aofs[1] + ko, &As[buf][(wid * 2 + 1) * 512]);
    gload_lds16(B + bofs + ko, &Bs[buf][wid * 512]);
  };

  stage(0, 0);
  if (nkt > 1) stage(1, 1);

  const int fr = lane & 15;
  const int s0 = (((lane >> 4) ^ ((fr >> 1) & 3)) << 3);

  int cur = 0;
  for (int kt = 0; kt < nkt; ++kt) {
    int nxt = cur + 2;
    if (nxt >= 3) nxt -= 3;
    if (kt + 2 < nkt) {
      stage(nxt, kt + 2);
      asm volatile("s_waitcnt vmcnt(6)" ::: "memory");
    } else if (kt + 1 < nkt) {
      asm volatile("s_waitcnt vmcnt(3)" ::: "memory");
    } else {
      asm volatile("s_waitcnt vmcnt(0)" ::: "memory");
    }
    __builtin_amdgcn_s_barrier();

    bf16x8 af[4], bfr[4];
#pragma unroll
    for (int m = 0; m < 4; ++m)
      af[m] = *(const bf16x8*)&As[cur][(wr * 64 + m * 16 + fr) * 32 + s0];
#pragma unroll
    for (int n = 0; n < 4; ++n)
      bfr[n] = *(const bf16x8*)&Bs[cur][(wc * 64 + n * 16 + fr) * 32 + s0];
#pragma unroll
    for (int m = 0; m < 4; ++m)
#pragma unroll
      for (int n = 0; n < 4; ++n)
        acc[m][n] = __builtin_amdgcn_mfma_f32_16x16x32_bf16(af[m], bfr[n], acc[m][n], 0, 0, 0);

    __builtin_amdgcn_s_barrier();
    cur += 1;
    if (cur >= 3) cur -= 3;
  }

  const int colBase = nblk * 128 + wc * 64 + (lane & 15);
  const int rowBase = mblk * 256 + wr * 64 + ((lane >> 4) << 2);
  const size_t outOfs = (size_t)half * 2 * NTOK * DH;
#pragma unroll
  for (int n = 0; n < 4; ++n) {
    const int c = colBase + n * 16;
    const float bv = half ? 0.0f : bias[c];
#pragma unroll
    for (int m = 0; m < 4; ++m) {
#pragma unroll
      for (int j = 0; j < 4; ++j) {
        const int r = rowBase + m * 16 + j;
        if (r < Mloc) {
          const int entry = myList[r];
          const float w = myW[r];
          Cbase[outOfs + (size_t)entry * DH + c] = (acc[m][n][j] + bv) * w;
        }
      }
    }
  }
}

// ---------------- launch ----------------

extern "C" void kernel_launch(void* const* d_in, const int* in_sizes, int n_in,
                              void* d_out, int out_size, void* d_ws, size_t ws_size,
                              hipStream_t stream) {
  const float* x      = (const float*)d_in[0];
  const float* W_in   = (const float*)d_in[1];
  const float* b_in   = (const float*)d_in[2];
  const float* W_gate = (const float*)d_in[3];
  const float* b_gate = (const float*)d_in[4];
  const float* W1     = (const float*)d_in[5];
  const float* b1     = (const float*)d_in[6];
  const float* W2     = (const float*)d_in[7];
  const float* b2     = (const float*)d_in[8];
  const float* W_out  = (const float*)d_in[9];
  const float* b_out  = (const float*)d_in[10];

  char* ws = (char*)d_ws;
  size_t off = 0;
  auto alloc = [&](size_t bytes) -> void* {
    void* p = ws + off;
    off += (bytes + 255) & ~(size_t)255;
    return p;
  };

  bf16_t* WtIn  = (bf16_t*)alloc((size_t)DH * DIN * 2);
  bf16_t* Wt1   = (bf16_t*)alloc((size_t)NEXP * DMOE * DH * 2);
  bf16_t* Wt2   = (bf16_t*)alloc((size_t)NEXP * DH * DMOE * 2);
  bf16_t* WtOut = (bf16_t*)alloc((size_t)DH * DH * 2);
  bf16_t* xbf   = (bf16_t*)alloc((size_t)NTOK * DIN * 2);
  bf16_t* hbf   = (bf16_t*)alloc((size_t)NTOK * DH * 2);
  bf16_t* mid   = (bf16_t*)alloc((size_t)2 * NTOK * DMOE * 2);
  float*  e32   = (float*)alloc((size_t)2 * 2 * NTOK * DH * 4);  // [half][2N][DH] fp32
  bf16_t* moebf = (bf16_t*)alloc((size_t)NTOK * DH * 2);
  double* G     = (double*)alloc((size_t)DIN * 8 * 8);
  double* cvec  = (double*)alloc(8 * 8);
  int*    cnt   = (int*)alloc(NEXP * 4);
  int*    offs  = (int*)alloc((NEXP + 1) * 4);
  int*    list  = (int*)alloc((size_t)NEXP * NTOK * 4);
  float*  wlist = (float*)alloc((size_t)NEXP * NTOK * 4);

  // 4 weight transposes + x cvt, one launch
  k_transpose_all<<<20992, 256, 0, stream>>>(W_in, W1, W2, W_out, x,
                                             WtIn, Wt1, Wt2, WtOut, xbf);

  k_gate_prep<<<64, 256, 0, stream>>>(W_in, W_gate, b_in, b_gate, G, cvec, cnt);
  k_gating<<<NTOK / 4, 256, 0, stream>>>(x, G, cvec, cnt, list, wlist);
  k_scan<<<1, 64, 0, stream>>>(cnt, offs);

  // h = x @ W_in + b_in  (bf16 out)
  k_gemm_plain<0><<<dim3(DH / 128, NTOK / 128, 1), 256, 0, stream>>>(
      xbf, WtIn, b_in, hbf, NTOK, DH, DIN);
  // mid = relu(h_gathered @ W1[e] + b1[e])  (256x128, 8 waves)
  k_gemm1<<<dim3(DMOE / 128, NTOK / 256, NEXP), 512, 0, stream>>>(
      hbf, Wt1, b1, mid, DMOE, DH, cnt, offs, list);
  // e32[half][entry] = ((mid @ W2[e][kh] + b2?half0) * route_w)  (split-K=2)
  k_gemm2s<<<dim3(DH / 128, NTOK / 256, NEXP * 2), 512, 0, stream>>>(
      mid, Wt2, b2, e32, DH, DMOE, cnt, offs, list, wlist);
  k_combine4<<<NTOK * DH / 4 / 256, 256, 0, stream>>>(e32, moebf);
  // out = moe @ W_out + b_out (fp32 out)
  k_gemm_plain<1><<<dim3(DH / 128, NTOK / 128, 1), 256, 0, stream>>>(
      moebf, WtOut, b_out, (float*)d_out, NTOK, DH, DH);
}

// Round 18
// 568.917 us; speedup vs baseline: 1.0241x; 1.0241x over previous
//
#include <hip/hip_runtime.h>
#include <hip/hip_bf16.h>

typedef __bf16 bf16_t;
typedef bf16_t bf16x8 __attribute__((ext_vector_type(8)));
typedef bf16_t bf16x4 __attribute__((ext_vector_type(4)));
typedef float f32x4 __attribute__((ext_vector_type(4)));

#define DIN 1024
#define DH 1024
#define DMOE 4096
#define NEXP 8
#define NTOK 4096

__device__ __forceinline__ void gload_lds16(const bf16_t* g, bf16_t* l) {
  __builtin_amdgcn_global_load_lds(
      (const __attribute__((address_space(1))) void*)g,
      (__attribute__((address_space(3))) void*)l, 16, 0, 0);
}

// ---------------- unified prep: 4 weight transposes + x cvt, one launch ----------
__global__ void k_transpose_all(const float* __restrict__ W_in, const float* __restrict__ W1,
                                const float* __restrict__ W2, const float* __restrict__ W_out,
                                const float* __restrict__ x,
                                bf16_t* __restrict__ WtIn, bf16_t* __restrict__ Wt1,
                                bf16_t* __restrict__ Wt2, bf16_t* __restrict__ WtOut,
                                bf16_t* __restrict__ xbf) {
  const int z = blockIdx.x;
  if (z >= 16896) {
    const int i = (z - 16896) * 256 + threadIdx.x;
    const float4 v = *(const float4*)(x + (size_t)i * 4);
    bf16x4 o;
    o.x = (bf16_t)v.x; o.y = (bf16_t)v.y; o.z = (bf16_t)v.z; o.w = (bf16_t)v.w;
    *(bf16x4*)(xbf + (size_t)i * 4) = o;
    return;
  }
  const float* s; bf16_t* d; int R, C, tx, ty;
  if (z < 256) {
    s = W_in; d = WtIn; R = DIN; C = DH; tx = z & 15; ty = z >> 4;
  } else if (z < 8448) {
    const int l = z - 256, e = l >> 10, t = l & 1023;
    s = W1 + (size_t)e * DH * DMOE; d = Wt1 + (size_t)e * DH * DMOE;
    R = DH; C = DMOE; tx = t & 63; ty = t >> 6;
  } else if (z < 16640) {
    const int l = z - 8448, e = l >> 10, t = l & 1023;
    s = W2 + (size_t)e * DMOE * DH; d = Wt2 + (size_t)e * DMOE * DH;
    R = DMOE; C = DH; tx = t & 15; ty = t >> 4;
  } else {
    const int t = z - 16640;
    s = W_out; d = WtOut; R = DH; C = DH; tx = t & 15; ty = t >> 4;
  }
  __shared__ float tile[64][65];
  const int c0 = tx * 64, r0 = ty * 64;
  const int t = threadIdx.x;
  const int rr = t >> 4;
  const int cc = (t & 15) << 2;
#pragma unroll
  for (int i = 0; i < 64; i += 16) {
    const float4 v = *(const float4*)&s[(size_t)(r0 + rr + i) * C + c0 + cc];
    tile[rr + i][cc + 0] = v.x;
    tile[rr + i][cc + 1] = v.y;
    tile[rr + i][cc + 2] = v.z;
    tile[rr + i][cc + 3] = v.w;
  }
  __syncthreads();
  const int orr = (t & 7) * 8;
  const int oc = t >> 3;
#pragma unroll
  for (int i = 0; i < 64; i += 32) {
    bf16x8 o;
#pragma unroll
    for (int j = 0; j < 8; ++j) o[j] = (bf16_t)tile[orr + j][oc + i];
    *(bf16x8*)&d[(size_t)(c0 + oc + i) * R + r0 + orr] = o;
  }
}

// G[d][e] = sum_k W_in[d][k] * W_gate[k][e]  (fp64); row d==DH computes c[e] from b_in.
__global__ void k_gate_prep(const float* __restrict__ Win, const float* __restrict__ Wgate,
                            const float* __restrict__ b_in, const float* __restrict__ b_gate,
                            double* __restrict__ G, double* __restrict__ cvec,
                            int* __restrict__ cnt) {
  if (blockIdx.x == 0 && threadIdx.x < 8) cnt[threadIdx.x] = 0;
  const int lane = threadIdx.x & 63;
  const int wave = (blockIdx.x * blockDim.x + threadIdx.x) >> 6;
  const int nw = (gridDim.x * blockDim.x) >> 6;
  for (int d = wave; d <= DIN; d += nw) {
    const float* row = (d < DIN) ? (Win + (size_t)d * DH) : b_in;
    double acc[8] = {0, 0, 0, 0, 0, 0, 0, 0};
    for (int k = lane; k < DH; k += 64) {
      const double xv = (double)row[k];
      const float* g = Wgate + (size_t)k * NEXP;
#pragma unroll
      for (int ee = 0; ee < 8; ++ee) acc[ee] += xv * (double)g[ee];
    }
#pragma unroll
    for (int ee = 0; ee < 8; ++ee) {
      double a = acc[ee];
      for (int o = 32; o > 0; o >>= 1) a += __shfl_down(a, o);
      acc[ee] = a;
    }
    if (lane == 0) {
      if (d < DIN) {
#pragma unroll
        for (int ee = 0; ee < 8; ++ee) G[(size_t)d * 8 + ee] = acc[ee];
      } else {
#pragma unroll
        for (int ee = 0; ee < 8; ++ee) cvec[ee] = acc[ee] + (double)b_gate[ee];
      }
    }
  }
}

// per token: fp64 logits via fused G, softmax, top-2, scatter into expert lists
__global__ void k_gating(const float* __restrict__ x, const double* __restrict__ G,
                         const double* __restrict__ cvec, int* __restrict__ cnt,
                         int* __restrict__ list, float* __restrict__ wlist) {
  const int lane = threadIdx.x & 63;
  const int t = blockIdx.x * (blockDim.x >> 6) + (threadIdx.x >> 6);
  if (t >= NTOK) return;
  const float* xr = x + (size_t)t * DIN;
  double acc[8] = {0, 0, 0, 0, 0, 0, 0, 0};
  for (int d = lane; d < DIN; d += 64) {
    const double xv = (double)xr[d];
    const double* g = G + (size_t)d * 8;
#pragma unroll
    for (int ee = 0; ee < 8; ++ee) acc[ee] += xv * g[ee];
  }
#pragma unroll
  for (int ee = 0; ee < 8; ++ee) {
    double a = acc[ee];
    for (int o = 32; o > 0; o >>= 1) a += __shfl_down(a, o);
    acc[ee] = a;
  }
  if (lane == 0) {
    double l[8];
#pragma unroll
    for (int ee = 0; ee < 8; ++ee) l[ee] = acc[ee] + cvec[ee];
    double m = l[0];
#pragma unroll
    for (int ee = 1; ee < 8; ++ee) m = fmax(m, l[ee]);
    double p[8];
#pragma unroll
    for (int ee = 0; ee < 8; ++ee) p[ee] = exp(l[ee] - m);
    int i1 = 0;
#pragma unroll
    for (int ee = 1; ee < 8; ++ee)
      if (p[ee] > p[i1]) i1 = ee;
    int i2 = (i1 == 0) ? 1 : 0;
#pragma unroll
    for (int ee = 0; ee < 8; ++ee)
      if (ee != i1 && p[ee] > p[i2]) i2 = ee;
    const double s2 = p[i1] + p[i2];
    const float w1 = (float)(p[i1] / s2);
    const float w2 = (float)(p[i2] / s2);
    int lp = atomicAdd(&cnt[i1], 1);
    list[i1 * NTOK + lp] = t * 2;
    wlist[i1 * NTOK + lp] = w1;
    lp = atomicAdd(&cnt[i2], 1);
    list[i2 * NTOK + lp] = t * 2 + 1;
    wlist[i2 * NTOK + lp] = w2;
  }
}

__global__ void k_scan(const int* __restrict__ cnt, int* __restrict__ offs) {
  if (threadIdx.x == 0) {
    int s = 0;
    for (int e = 0; e < NEXP; ++e) { offs[e] = s; s += cnt[e]; }
    offs[NEXP] = s;
  }
}

// moe_bf16[t] = bf16(sum of 4 bf16 partials: 2 slots x 2 K-halves)
__global__ void k_combine4(const bf16_t* __restrict__ ebf, bf16_t* __restrict__ moebf) {
  const int i = blockIdx.x * blockDim.x + threadIdx.x;
  const int t = i >> 8;
  const int q = (i & 255) * 4;
  const bf16x4 a = *(const bf16x4*)(ebf + ((size_t)t * 2) * DH + q);
  const bf16x4 b = *(const bf16x4*)(ebf + ((size_t)t * 2 + 1) * DH + q);
  const bf16x4 c = *(const bf16x4*)(ebf + ((size_t)(2 * NTOK + t * 2)) * DH + q);
  const bf16x4 d = *(const bf16x4*)(ebf + ((size_t)(2 * NTOK + t * 2 + 1)) * DH + q);
  bf16x4 o;
  o.x = (bf16_t)((float)a.x + (float)b.x + (float)c.x + (float)d.x);
  o.y = (bf16_t)((float)a.y + (float)b.y + (float)c.y + (float)d.y);
  o.z = (bf16_t)((float)a.z + (float)b.z + (float)c.z + (float)d.z);
  o.w = (bf16_t)((float)a.w + (float)b.w + (float)c.w + (float)d.w);
  *(bf16x4*)(moebf + (size_t)t * DH + q) = o;
}

// ---------------- 128x128 BK=32 plain GEMM, 4 waves (R10 structure) ----------
template <int OUT_F32>
__global__ __launch_bounds__(256, 3) void k_gemm_plain(
    const bf16_t* __restrict__ A, const bf16_t* __restrict__ B,
    const float* __restrict__ bias, void* __restrict__ Cbase,
    int M, int N, int K) {
  const int mblk = blockIdx.y, nblk = blockIdx.x;

  __shared__ bf16_t As[3][128 * 32];
  __shared__ bf16_t Bs[3][128 * 32];

  const int tid = threadIdx.x;
  const int lane = tid & 63;
  const int wid = tid >> 6;
  const int wr = wid >> 1, wc = wid & 1;

  const int srow0 = wid * 32 + (lane >> 2);
  const int srow1 = srow0 + 16;
  const int skcol = ((lane & 3) ^ ((lane >> 3) & 3)) * 8;

  const bf16_t* aptr0 = A + (size_t)(mblk * 128 + srow0) * K + skcol;
  const bf16_t* aptr1 = A + (size_t)(mblk * 128 + srow1) * K + skcol;
  const bf16_t* bptr0 = B + (size_t)(nblk * 128 + srow0) * K + skcol;
  const bf16_t* bptr1 = B + (size_t)(nblk * 128 + srow1) * K + skcol;

  const int ldsOfsA0 = (wid * 32) * 32;
  const int ldsOfsA1 = (wid * 32 + 16) * 32;

  f32x4 acc[4][4] = {};
  const int nkt = K >> 5;

  auto stage = [&](int buf, int kt) {
    const size_t ko = (size_t)kt * 32;
    gload_lds16(aptr0 + ko, &As[buf][ldsOfsA0]);
    gload_lds16(aptr1 + ko, &As[buf][ldsOfsA1]);
    gload_lds16(bptr0 + ko, &Bs[buf][ldsOfsA0]);
    gload_lds16(bptr1 + ko, &Bs[buf][ldsOfsA1]);
  };

  stage(0, 0);
  if (nkt > 1) stage(1, 1);

  const int fr = lane & 15;
  const int s0 = (((lane >> 4) ^ ((fr >> 1) & 3)) << 3);

  int cur = 0;
  for (int kt = 0; kt < nkt; ++kt) {
    int nxt = cur + 2;
    if (nxt >= 3) nxt -= 3;
    if (kt + 2 < nkt) {
      stage(nxt, kt + 2);
      asm volatile("s_waitcnt vmcnt(8)" ::: "memory");
    } else if (kt + 1 < nkt) {
      asm volatile("s_waitcnt vmcnt(4)" ::: "memory");
    } else {
      asm volatile("s_waitcnt vmcnt(0)" ::: "memory");
    }
    __builtin_amdgcn_s_barrier();

    bf16x8 af[4], bfr[4];
#pragma unroll
    for (int m = 0; m < 4; ++m)
      af[m] = *(const bf16x8*)&As[cur][(wr * 64 + m * 16 + fr) * 32 + s0];
#pragma unroll
    for (int n = 0; n < 4; ++n)
      bfr[n] = *(const bf16x8*)&Bs[cur][(wc * 64 + n * 16 + fr) * 32 + s0];
#pragma unroll
    for (int m = 0; m < 4; ++m)
#pragma unroll
      for (int n = 0; n < 4; ++n)
        acc[m][n] = __builtin_amdgcn_mfma_f32_16x16x32_bf16(af[m], bfr[n], acc[m][n], 0, 0, 0);

    __builtin_amdgcn_s_barrier();
    cur += 1;
    if (cur >= 3) cur -= 3;
  }

  const int colBase = nblk * 128 + wc * 64 + (lane & 15);
  const int rowBase = mblk * 128 + wr * 64 + ((lane >> 4) << 2);
#pragma unroll
  for (int n = 0; n < 4; ++n) {
    const int c = colBase + n * 16;
    const float bv = bias[c];
#pragma unroll
    for (int m = 0; m < 4; ++m) {
#pragma unroll
      for (int j = 0; j < 4; ++j) {
        const int r = rowBase + m * 16 + j;
        const float v = acc[m][n][j] + bv;
        if constexpr (OUT_F32 == 0) {
          ((bf16_t*)Cbase)[(size_t)r * N + c] = (bf16_t)v;
        } else {
          ((float*)Cbase)[(size_t)r * N + c] = v;
        }
      }
    }
  }
}

// ---------------- 256x128 BK=32 expert GEMM1, 8 waves (R15-proven) ------
__global__ __launch_bounds__(512, 4) void k_gemm1(
    const bf16_t* __restrict__ Abase, const bf16_t* __restrict__ Bbase,
    const float* __restrict__ biasBase, bf16_t* __restrict__ Cbase,
    int N, int K,
    const int* __restrict__ cnt, const int* __restrict__ offs,
    const int* __restrict__ listBase) {
  const int e = blockIdx.z;
  const int mblk = blockIdx.y, nblk = blockIdx.x;
  const int Mloc = cnt[e];
  if (mblk * 256 >= Mloc) return;
  const bf16_t* B = Bbase + (size_t)e * N * K;
  const float* bias = biasBase + (size_t)e * N;
  const int* myList = listBase + e * NTOK;
  const int rowOff = offs[e];

  __shared__ bf16_t As[3][256 * 32];
  __shared__ bf16_t Bs[3][128 * 32];

  const int tid = threadIdx.x;
  const int lane = tid & 63;
  const int wid = tid >> 6;
  const int wr = wid >> 1, wc = wid & 1;

  const int subr = lane >> 2;
  const int skcol = ((lane & 3) ^ ((lane >> 3) & 3)) * 8;

  uint32_t aofs[2];
#pragma unroll
  for (int l = 0; l < 2; ++l) {
    int ar = mblk * 256 + (wid * 2 + l) * 16 + subr;
    if (ar > Mloc - 1) ar = Mloc - 1;
    aofs[l] = (uint32_t)(myList[ar] >> 1) * (uint32_t)K + skcol;
  }
  const uint32_t bofs = (uint32_t)(nblk * 128 + wid * 16 + subr) * (uint32_t)K + skcol;

  f32x4 acc[4][4] = {};
  const int nkt = K >> 5;

  auto stage = [&](int buf, int kt) {
    const uint32_t ko = (uint32_t)kt * 32;
    gload_lds16(Abase + aofs[0] + ko, &As[buf][(wid * 2 + 0) * 512]);
    gload_lds16(Abase + aofs[1] + ko, &As[buf][(wid * 2 + 1) * 512]);
    gload_lds16(B + bofs + ko, &Bs[buf][wid * 512]);
  };

  stage(0, 0);
  if (nkt > 1) stage(1, 1);

  const int fr = lane & 15;
  const int s0 = (((lane >> 4) ^ ((fr >> 1) & 3)) << 3);

  int cur = 0;
  for (int kt = 0; kt < nkt; ++kt) {
    int nxt = cur + 2;
    if (nxt >= 3) nxt -= 3;
    if (kt + 2 < nkt) {
      stage(nxt, kt + 2);
      asm volatile("s_waitcnt vmcnt(6)" ::: "memory");
    } else if (kt + 1 < nkt) {
      asm volatile("s_waitcnt vmcnt(3)" ::: "memory");
    } else {
      asm volatile("s_waitcnt vmcnt(0)" ::: "memory");
    }
    __builtin_amdgcn_s_barrier();

    bf16x8 af[4], bfr[4];
#pragma unroll
    for (int m = 0; m < 4; ++m)
      af[m] = *(const bf16x8*)&As[cur][(wr * 64 + m * 16 + fr) * 32 + s0];
#pragma unroll
    for (int n = 0; n < 4; ++n)
      bfr[n] = *(const bf16x8*)&Bs[cur][(wc * 64 + n * 16 + fr) * 32 + s0];
#pragma unroll
    for (int m = 0; m < 4; ++m)
#pragma unroll
      for (int n = 0; n < 4; ++n)
        acc[m][n] = __builtin_amdgcn_mfma_f32_16x16x32_bf16(af[m], bfr[n], acc[m][n], 0, 0, 0);

    __builtin_amdgcn_s_barrier();
    cur += 1;
    if (cur >= 3) cur -= 3;
  }

  const int colBase = nblk * 128 + wc * 64 + (lane & 15);
  const int rowBase = mblk * 256 + wr * 64 + ((lane >> 4) << 2);
#pragma unroll
  for (int n = 0; n < 4; ++n) {
    const int c = colBase + n * 16;
    const float bv = bias[c];
#pragma unroll
    for (int m = 0; m < 4; ++m) {
#pragma unroll
      for (int j = 0; j < 4; ++j) {
        const int r = rowBase + m * 16 + j;
        if (r < Mloc) {
          Cbase[(size_t)(rowOff + r) * N + c] = (bf16_t)fmaxf(acc[m][n][j] + bv, 0.0f);
        }
      }
    }
  }
}

// ---------------- 128x128 BK=32 split-K=2 expert GEMM2, 4 waves ------------------
// z = e*2+half; block computes K-half [half*K/2, ...).  A contiguous (mid+offs[e]).
// bf16 partial out: ebf[half*2N + entry][c] = bf16((acc + bias?half0) * w).
// 1024 active blocks at 3/CU; serial chain halved (64 K-tiles vs 128).
__global__ __launch_bounds__(256, 3) void k_gemm2s(
    const bf16_t* __restrict__ Abase, const bf16_t* __restrict__ Bbase,
    const float* __restrict__ biasBase, bf16_t* __restrict__ Cbase,
    int N, int K,
    const int* __restrict__ cnt, const int* __restrict__ offs,
    const int* __restrict__ listBase, const float* __restrict__ wlistBase) {
  const int e = blockIdx.z >> 1;
  const int half = blockIdx.z & 1;
  const int mblk = blockIdx.y, nblk = blockIdx.x;
  const int Mloc = cnt[e];
  if (mblk * 128 >= Mloc) return;  // uniform early exit, before any barrier
  const bf16_t* B = Bbase + (size_t)e * N * K;
  const float* bias = biasBase + (size_t)e * N;
  const int* myList = listBase + e * NTOK;
  const float* myW = wlistBase + e * NTOK;
  const bf16_t* A = Abase + (size_t)offs[e] * K;
  const uint32_t kbase = (uint32_t)half * (uint32_t)(K >> 1);

  __shared__ bf16_t As[3][128 * 32];
  __shared__ bf16_t Bs[3][128 * 32];

  const int tid = threadIdx.x;
  const int lane = tid & 63;
  const int wid = tid >> 6;
  const int wr = wid >> 1, wc = wid & 1;

  const int srow0 = wid * 32 + (lane >> 2);
  const int srow1 = srow0 + 16;
  const int skcol = ((lane & 3) ^ ((lane >> 3) & 3)) * 8;

  int ar0 = mblk * 128 + srow0;
  int ar1 = mblk * 128 + srow1;
  if (ar0 > Mloc - 1) ar0 = Mloc - 1;
  if (ar1 > Mloc - 1) ar1 = Mloc - 1;
  const bf16_t* aptr0 = A + (size_t)ar0 * K + kbase + skcol;
  const bf16_t* aptr1 = A + (size_t)ar1 * K + kbase + skcol;
  const bf16_t* bptr0 = B + (size_t)(nblk * 128 + srow0) * K + kbase + skcol;
  const bf16_t* bptr1 = B + (size_t)(nblk * 128 + srow1) * K + kbase + skcol;

  const int ldsOfsA0 = (wid * 32) * 32;
  const int ldsOfsA1 = (wid * 32 + 16) * 32;

  f32x4 acc[4][4] = {};
  const int nkt = K >> 6;  // half-K in BK=32 tiles

  auto stage = [&](int buf, int kt) {
    const size_t ko = (size_t)kt * 32;
    gload_lds16(aptr0 + ko, &As[buf][ldsOfsA0]);
    gload_lds16(aptr1 + ko, &As[buf][ldsOfsA1]);
    gload_lds16(bptr0 + ko, &Bs[buf][ldsOfsA0]);
    gload_lds16(bptr1 + ko, &Bs[buf][ldsOfsA1]);
  };

  stage(0, 0);
  if (nkt > 1) stage(1, 1);

  const int fr = lane & 15;
  const int s0 = (((lane >> 4) ^ ((fr >> 1) & 3)) << 3);

  int cur = 0;
  for (int kt = 0; kt < nkt; ++kt) {
    int nxt = cur + 2;
    if (nxt >= 3) nxt -= 3;
    if (kt + 2 < nkt) {
      stage(nxt, kt + 2);
      asm volatile("s_waitcnt vmcnt(8)" ::: "memory");
    } else if (kt + 1 < nkt) {
      asm volatile("s_waitcnt vmcnt(4)" ::: "memory");
    } else {
      asm volatile("s_waitcnt vmcnt(0)" ::: "memory");
    }
    __builtin_amdgcn_s_barrier();

    bf16x8 af[4], bfr[4];
#pragma unroll
    for (int m = 0; m < 4; ++m)
      af[m] = *(const bf16x8*)&As[cur][(wr * 64 + m * 16 + fr) * 32 + s0];
#pragma unroll
    for (int n = 0; n < 4; ++n)
      bfr[n] = *(const bf16x8*)&Bs[cur][(wc * 64 + n * 16 + fr) * 32 + s0];
#pragma unroll
    for (int m = 0; m < 4; ++m)
#pragma unroll
      for (int n = 0; n < 4; ++n)
        acc[m][n] = __builtin_amdgcn_mfma_f32_16x16x32_bf16(af[m], bfr[n], acc[m][n], 0, 0, 0);

    __builtin_amdgcn_s_barrier();
    cur += 1;
    if (cur >= 3) cur -= 3;
  }

  const int colBase = nblk * 128 + wc * 64 + (lane & 15);
  const int rowBase = mblk * 128 + wr * 64 + ((lane >> 4) << 2);
  const size_t outOfs = (size_t)half * 2 * NTOK * DH;
#pragma unroll
  for (int n = 0; n < 4; ++n) {
    const int c = colBase + n * 16;
    const float bv = half ? 0.0f : bias[c];
#pragma unroll
    for (int m = 0; m < 4; ++m) {
#pragma unroll
      for (int j = 0; j < 4; ++j) {
        const int r = rowBase + m * 16 + j;
        if (r < Mloc) {
          const int entry = myList[r];
          const float w = myW[r];
          Cbase[outOfs + (size_t)entry * DH + c] = (bf16_t)((acc[m][n][j] + bv) * w);
        }
      }
    }
  }
}

// ---------------- launch ----------------

extern "C" void kernel_launch(void* const* d_in, const int* in_sizes, int n_in,
                              void* d_out, int out_size, void* d_ws, size_t ws_size,
                              hipStream_t stream) {
  const float* x      = (const float*)d_in[0];
  const float* W_in   = (const float*)d_in[1];
  const float* b_in   = (const float*)d_in[2];
  const float* W_gate = (const float*)d_in[3];
  const float* b_gate = (const float*)d_in[4];
  const float* W1     = (const float*)d_in[5];
  const float* b1     = (const float*)d_in[6];
  const float* W2     = (const float*)d_in[7];
  const float* b2     = (const float*)d_in[8];
  const float* W_out  = (const float*)d_in[9];
  const float* b_out  = (const float*)d_in[10];

  char* ws = (char*)d_ws;
  size_t off = 0;
  auto alloc = [&](size_t bytes) -> void* {
    void* p = ws + off;
    off += (bytes + 255) & ~(size_t)255;
    return p;
  };

  bf16_t* WtIn  = (bf16_t*)alloc((size_t)DH * DIN * 2);
  bf16_t* Wt1   = (bf16_t*)alloc((size_t)NEXP * DMOE * DH * 2);
  bf16_t* Wt2   = (bf16_t*)alloc((size_t)NEXP * DH * DMOE * 2);
  bf16_t* WtOut = (bf16_t*)alloc((size_t)DH * DH * 2);
  bf16_t* xbf   = (bf16_t*)alloc((size_t)NTOK * DIN * 2);
  bf16_t* hbf   = (bf16_t*)alloc((size_t)NTOK * DH * 2);
  bf16_t* mid   = (bf16_t*)alloc((size_t)2 * NTOK * DMOE * 2);
  bf16_t* ebf   = (bf16_t*)alloc((size_t)2 * 2 * NTOK * DH * 2);  // [half][2N][DH] bf16
  bf16_t* moebf = (bf16_t*)alloc((size_t)NTOK * DH * 2);
  double* G     = (double*)alloc((size_t)DIN * 8 * 8);
  double* cvec  = (double*)alloc(8 * 8);
  int*    cnt   = (int*)alloc(NEXP * 4);
  int*    offs  = (int*)alloc((NEXP + 1) * 4);
  int*    list  = (int*)alloc((size_t)NEXP * NTOK * 4);
  float*  wlist = (float*)alloc((size_t)NEXP * NTOK * 4);

  k_transpose_all<<<20992, 256, 0, stream>>>(W_in, W1, W2, W_out, x,
                                             WtIn, Wt1, Wt2, WtOut, xbf);

  k_gate_prep<<<64, 256, 0, stream>>>(W_in, W_gate, b_in, b_gate, G, cvec, cnt);
  k_gating<<<NTOK / 4, 256, 0, stream>>>(x, G, cvec, cnt, list, wlist);
  k_scan<<<1, 64, 0, stream>>>(cnt, offs);

  // h = x @ W_in + b_in  (bf16 out)
  k_gemm_plain<0><<<dim3(DH / 128, NTOK / 128, 1), 256, 0, stream>>>(
      xbf, WtIn, b_in, hbf, NTOK, DH, DIN);
  // mid = relu(h_gathered @ W1[e] + b1[e])  (256x128, 8 waves)
  k_gemm1<<<dim3(DMOE / 128, NTOK / 256, NEXP), 512, 0, stream>>>(
      hbf, Wt1, b1, mid, DMOE, DH, cnt, offs, list);
  // ebf[half][entry] = bf16(((mid @ W2[e][kh]) + b2?half0) * route_w)  (split-K=2, 128^2)
  k_gemm2s<<<dim3(DH / 128, NTOK / 128, NEXP * 2), 256, 0, stream>>>(
      mid, Wt2, b2, ebf, DH, DMOE, cnt, offs, list, wlist);
  k_combine4<<<NTOK * DH / 4 / 256, 256, 0, stream>>>(ebf, moebf);
  // out = moe @ W_out + b_out (fp32 out)
  k_gemm_plain<1><<<dim3(DH / 128, NTOK / 128, 1), 256, 0, stream>>>(
      moebf, WtOut, b_out, (float*)d_out, NTOK, DH, DH);
}

// Round 19
// 556.527 us; speedup vs baseline: 1.0469x; 1.0223x over previous
//
#include <hip/hip_runtime.h>
#include <hip/hip_bf16.h>

typedef __bf16 bf16_t;
typedef bf16_t bf16x8 __attribute__((ext_vector_type(8)));
typedef bf16_t bf16x4 __attribute__((ext_vector_type(4)));
typedef float f32x4 __attribute__((ext_vector_type(4)));

#define DIN 1024
#define DH 1024
#define DMOE 4096
#define NEXP 8
#define NTOK 4096

__device__ __forceinline__ void gload_lds16(const bf16_t* g, bf16_t* l) {
  __builtin_amdgcn_global_load_lds(
      (const __attribute__((address_space(1))) void*)g,
      (__attribute__((address_space(3))) void*)l, 16, 0, 0);
}

// ---------------- unified prep: 4 weight transposes + x cvt, one launch ----------
__global__ void k_transpose_all(const float* __restrict__ W_in, const float* __restrict__ W1,
                                const float* __restrict__ W2, const float* __restrict__ W_out,
                                const float* __restrict__ x,
                                bf16_t* __restrict__ WtIn, bf16_t* __restrict__ Wt1,
                                bf16_t* __restrict__ Wt2, bf16_t* __restrict__ WtOut,
                                bf16_t* __restrict__ xbf) {
  const int z = blockIdx.x;
  if (z >= 16896) {
    const int i = (z - 16896) * 256 + threadIdx.x;
    const float4 v = *(const float4*)(x + (size_t)i * 4);
    bf16x4 o;
    o.x = (bf16_t)v.x; o.y = (bf16_t)v.y; o.z = (bf16_t)v.z; o.w = (bf16_t)v.w;
    *(bf16x4*)(xbf + (size_t)i * 4) = o;
    return;
  }
  const float* s; bf16_t* d; int R, C, tx, ty;
  if (z < 256) {
    s = W_in; d = WtIn; R = DIN; C = DH; tx = z & 15; ty = z >> 4;
  } else if (z < 8448) {
    const int l = z - 256, e = l >> 10, t = l & 1023;
    s = W1 + (size_t)e * DH * DMOE; d = Wt1 + (size_t)e * DH * DMOE;
    R = DH; C = DMOE; tx = t & 63; ty = t >> 6;
  } else if (z < 16640) {
    const int l = z - 8448, e = l >> 10, t = l & 1023;
    s = W2 + (size_t)e * DMOE * DH; d = Wt2 + (size_t)e * DMOE * DH;
    R = DMOE; C = DH; tx = t & 15; ty = t >> 4;
  } else {
    const int t = z - 16640;
    s = W_out; d = WtOut; R = DH; C = DH; tx = t & 15; ty = t >> 4;
  }
  __shared__ float tile[64][65];
  const int c0 = tx * 64, r0 = ty * 64;
  const int t = threadIdx.x;
  const int rr = t >> 4;
  const int cc = (t & 15) << 2;
#pragma unroll
  for (int i = 0; i < 64; i += 16) {
    const float4 v = *(const float4*)&s[(size_t)(r0 + rr + i) * C + c0 + cc];
    tile[rr + i][cc + 0] = v.x;
    tile[rr + i][cc + 1] = v.y;
    tile[rr + i][cc + 2] = v.z;
    tile[rr + i][cc + 3] = v.w;
  }
  __syncthreads();
  const int orr = (t & 7) * 8;
  const int oc = t >> 3;
#pragma unroll
  for (int i = 0; i < 64; i += 32) {
    bf16x8 o;
#pragma unroll
    for (int j = 0; j < 8; ++j) o[j] = (bf16_t)tile[orr + j][oc + i];
    *(bf16x8*)&d[(size_t)(c0 + oc + i) * R + r0 + orr] = o;
  }
}

// G[d][e] = sum_k W_in[d][k] * W_gate[k][e]  (fp64); row d==DH computes c[e] from b_in.
__global__ void k_gate_prep(const float* __restrict__ Win, const float* __restrict__ Wgate,
                            const float* __restrict__ b_in, const float* __restrict__ b_gate,
                            double* __restrict__ G, double* __restrict__ cvec,
                            int* __restrict__ cnt) {
  if (blockIdx.x == 0 && threadIdx.x < 8) cnt[threadIdx.x] = 0;
  const int lane = threadIdx.x & 63;
  const int wave = (blockIdx.x * blockDim.x + threadIdx.x) >> 6;
  const int nw = (gridDim.x * blockDim.x) >> 6;
  for (int d = wave; d <= DIN; d += nw) {
    const float* row = (d < DIN) ? (Win + (size_t)d * DH) : b_in;
    double acc[8] = {0, 0, 0, 0, 0, 0, 0, 0};
    for (int k = lane; k < DH; k += 64) {
      const double xv = (double)row[k];
      const float* g = Wgate + (size_t)k * NEXP;
#pragma unroll
      for (int ee = 0; ee < 8; ++ee) acc[ee] += xv * (double)g[ee];
    }
#pragma unroll
    for (int ee = 0; ee < 8; ++ee) {
      double a = acc[ee];
      for (int o = 32; o > 0; o >>= 1) a += __shfl_down(a, o);
      acc[ee] = a;
    }
    if (lane == 0) {
      if (d < DIN) {
#pragma unroll
        for (int ee = 0; ee < 8; ++ee) G[(size_t)d * 8 + ee] = acc[ee];
      } else {
#pragma unroll
        for (int ee = 0; ee < 8; ++ee) cvec[ee] = acc[ee] + (double)b_gate[ee];
      }
    }
  }
}

// per token: fp64 logits via fused G, softmax, top-2, scatter into expert lists
__global__ void k_gating(const float* __restrict__ x, const double* __restrict__ G,
                         const double* __restrict__ cvec, int* __restrict__ cnt,
                         int* __restrict__ list, float* __restrict__ wlist) {
  const int lane = threadIdx.x & 63;
  const int t = blockIdx.x * (blockDim.x >> 6) + (threadIdx.x >> 6);
  if (t >= NTOK) return;
  const float* xr = x + (size_t)t * DIN;
  double acc[8] = {0, 0, 0, 0, 0, 0, 0, 0};
  for (int d = lane; d < DIN; d += 64) {
    const double xv = (double)xr[d];
    const double* g = G + (size_t)d * 8;
#pragma unroll
    for (int ee = 0; ee < 8; ++ee) acc[ee] += xv * g[ee];
  }
#pragma unroll
  for (int ee = 0; ee < 8; ++ee) {
    double a = acc[ee];
    for (int o = 32; o > 0; o >>= 1) a += __shfl_down(a, o);
    acc[ee] = a;
  }
  if (lane == 0) {
    double l[8];
#pragma unroll
    for (int ee = 0; ee < 8; ++ee) l[ee] = acc[ee] + cvec[ee];
    double m = l[0];
#pragma unroll
    for (int ee = 1; ee < 8; ++ee) m = fmax(m, l[ee]);
    double p[8];
#pragma unroll
    for (int ee = 0; ee < 8; ++ee) p[ee] = exp(l[ee] - m);
    int i1 = 0;
#pragma unroll
    for (int ee = 1; ee < 8; ++ee)
      if (p[ee] > p[i1]) i1 = ee;
    int i2 = (i1 == 0) ? 1 : 0;
#pragma unroll
    for (int ee = 0; ee < 8; ++ee)
      if (ee != i1 && p[ee] > p[i2]) i2 = ee;
    const double s2 = p[i1] + p[i2];
    const float w1 = (float)(p[i1] / s2);
    const float w2 = (float)(p[i2] / s2);
    int lp = atomicAdd(&cnt[i1], 1);
    list[i1 * NTOK + lp] = t * 2;
    wlist[i1 * NTOK + lp] = w1;
    lp = atomicAdd(&cnt[i2], 1);
    list[i2 * NTOK + lp] = t * 2 + 1;
    wlist[i2 * NTOK + lp] = w2;
  }
}

// moe_bf16[t] = bf16(eout[t][0] + eout[t][1])
__global__ void k_combine(const bf16_t* __restrict__ eout, bf16_t* __restrict__ moebf) {
  const int i = blockIdx.x * blockDim.x + threadIdx.x;
  const int t = i >> 8;
  const int q = (i & 255) * 4;
  const bf16x4 a = *(const bf16x4*)(eout + ((size_t)t * 2) * DH + q);
  const bf16x4 b = *(const bf16x4*)(eout + ((size_t)t * 2 + 1) * DH + q);
  bf16x4 o;
  o.x = (bf16_t)((float)a.x + (float)b.x);
  o.y = (bf16_t)((float)a.y + (float)b.y);
  o.z = (bf16_t)((float)a.z + (float)b.z);
  o.w = (bf16_t)((float)a.w + (float)b.w);
  *(bf16x4*)(moebf + (size_t)t * DH + q) = o;
}

// ---------------- 128x128 BK=32 plain GEMM, 4 waves (R10 structure) ----------
template <int OUT_F32>
__global__ __launch_bounds__(256, 3) void k_gemm_plain(
    const bf16_t* __restrict__ A, const bf16_t* __restrict__ B,
    const float* __restrict__ bias, void* __restrict__ Cbase,
    int M, int N, int K) {
  const int mblk = blockIdx.y, nblk = blockIdx.x;

  __shared__ bf16_t As[3][128 * 32];
  __shared__ bf16_t Bs[3][128 * 32];

  const int tid = threadIdx.x;
  const int lane = tid & 63;
  const int wid = tid >> 6;
  const int wr = wid >> 1, wc = wid & 1;

  const int srow0 = wid * 32 + (lane >> 2);
  const int srow1 = srow0 + 16;
  const int skcol = ((lane & 3) ^ ((lane >> 3) & 3)) * 8;

  const bf16_t* aptr0 = A + (size_t)(mblk * 128 + srow0) * K + skcol;
  const bf16_t* aptr1 = A + (size_t)(mblk * 128 + srow1) * K + skcol;
  const bf16_t* bptr0 = B + (size_t)(nblk * 128 + srow0) * K + skcol;
  const bf16_t* bptr1 = B + (size_t)(nblk * 128 + srow1) * K + skcol;

  const int ldsOfsA0 = (wid * 32) * 32;
  const int ldsOfsA1 = (wid * 32 + 16) * 32;

  f32x4 acc[4][4] = {};
  const int nkt = K >> 5;

  auto stage = [&](int buf, int kt) {
    const size_t ko = (size_t)kt * 32;
    gload_lds16(aptr0 + ko, &As[buf][ldsOfsA0]);
    gload_lds16(aptr1 + ko, &As[buf][ldsOfsA1]);
    gload_lds16(bptr0 + ko, &Bs[buf][ldsOfsA0]);
    gload_lds16(bptr1 + ko, &Bs[buf][ldsOfsA1]);
  };

  stage(0, 0);
  if (nkt > 1) stage(1, 1);

  const int fr = lane & 15;
  const int s0 = (((lane >> 4) ^ ((fr >> 1) & 3)) << 3);

  int cur = 0;
  for (int kt = 0; kt < nkt; ++kt) {
    int nxt = cur + 2;
    if (nxt >= 3) nxt -= 3;
    if (kt + 2 < nkt) {
      stage(nxt, kt + 2);
      asm volatile("s_waitcnt vmcnt(8)" ::: "memory");
    } else if (kt + 1 < nkt) {
      asm volatile("s_waitcnt vmcnt(4)" ::: "memory");
    } else {
      asm volatile("s_waitcnt vmcnt(0)" ::: "memory");
    }
    __builtin_amdgcn_s_barrier();

    bf16x8 af[4], bfr[4];
#pragma unroll
    for (int m = 0; m < 4; ++m)
      af[m] = *(const bf16x8*)&As[cur][(wr * 64 + m * 16 + fr) * 32 + s0];
#pragma unroll
    for (int n = 0; n < 4; ++n)
      bfr[n] = *(const bf16x8*)&Bs[cur][(wc * 64 + n * 16 + fr) * 32 + s0];
#pragma unroll
    for (int m = 0; m < 4; ++m)
#pragma unroll
      for (int n = 0; n < 4; ++n)
        acc[m][n] = __builtin_amdgcn_mfma_f32_16x16x32_bf16(af[m], bfr[n], acc[m][n], 0, 0, 0);

    __builtin_amdgcn_s_barrier();
    cur += 1;
    if (cur >= 3) cur -= 3;
  }

  const int colBase = nblk * 128 + wc * 64 + (lane & 15);
  const int rowBase = mblk * 128 + wr * 64 + ((lane >> 4) << 2);
#pragma unroll
  for (int n = 0; n < 4; ++n) {
    const int c = colBase + n * 16;
    const float bv = bias[c];
#pragma unroll
    for (int m = 0; m < 4; ++m) {
#pragma unroll
      for (int j = 0; j < 4; ++j) {
        const int r = rowBase + m * 16 + j;
        const float v = acc[m][n][j] + bv;
        if constexpr (OUT_F32 == 0) {
          ((bf16_t*)Cbase)[(size_t)r * N + c] = (bf16_t)v;
        } else {
          ((float*)Cbase)[(size_t)r * N + c] = v;
        }
      }
    }
  }
}

// ---------------- 256x128 BK=32 expert GEMM1, 8 waves (R15-proven) ------
// offs[e] computed inline from cnt (k_scan launch removed).
__global__ __launch_bounds__(512, 4) void k_gemm1(
    const bf16_t* __restrict__ Abase, const bf16_t* __restrict__ Bbase,
    const float* __restrict__ biasBase, bf16_t* __restrict__ Cbase,
    int N, int K,
    const int* __restrict__ cnt, const int* __restrict__ listBase) {
  const int e = blockIdx.z;
  const int mblk = blockIdx.y, nblk = blockIdx.x;
  const int Mloc = cnt[e];
  if (mblk * 256 >= Mloc) return;
  int rowOff = 0;
  for (int i = 0; i < NEXP; ++i) rowOff += (i < e) ? cnt[i] : 0;
  const bf16_t* B = Bbase + (size_t)e * N * K;
  const float* bias = biasBase + (size_t)e * N;
  const int* myList = listBase + e * NTOK;

  __shared__ bf16_t As[3][256 * 32];
  __shared__ bf16_t Bs[3][128 * 32];

  const int tid = threadIdx.x;
  const int lane = tid & 63;
  const int wid = tid >> 6;
  const int wr = wid >> 1, wc = wid & 1;

  const int subr = lane >> 2;
  const int skcol = ((lane & 3) ^ ((lane >> 3) & 3)) * 8;

  uint32_t aofs[2];
#pragma unroll
  for (int l = 0; l < 2; ++l) {
    int ar = mblk * 256 + (wid * 2 + l) * 16 + subr;
    if (ar > Mloc - 1) ar = Mloc - 1;
    aofs[l] = (uint32_t)(myList[ar] >> 1) * (uint32_t)K + skcol;
  }
  const uint32_t bofs = (uint32_t)(nblk * 128 + wid * 16 + subr) * (uint32_t)K + skcol;

  f32x4 acc[4][4] = {};
  const int nkt = K >> 5;

  auto stage = [&](int buf, int kt) {
    const uint32_t ko = (uint32_t)kt * 32;
    gload_lds16(Abase + aofs[0] + ko, &As[buf][(wid * 2 + 0) * 512]);
    gload_lds16(Abase + aofs[1] + ko, &As[buf][(wid * 2 + 1) * 512]);
    gload_lds16(B + bofs + ko, &Bs[buf][wid * 512]);
  };

  stage(0, 0);
  if (nkt > 1) stage(1, 1);

  const int fr = lane & 15;
  const int s0 = (((lane >> 4) ^ ((fr >> 1) & 3)) << 3);

  int cur = 0;
  for (int kt = 0; kt < nkt; ++kt) {
    int nxt = cur + 2;
    if (nxt >= 3) nxt -= 3;
    if (kt + 2 < nkt) {
      stage(nxt, kt + 2);
      asm volatile("s_waitcnt vmcnt(6)" ::: "memory");
    } else if (kt + 1 < nkt) {
      asm volatile("s_waitcnt vmcnt(3)" ::: "memory");
    } else {
      asm volatile("s_waitcnt vmcnt(0)" ::: "memory");
    }
    __builtin_amdgcn_s_barrier();

    bf16x8 af[4], bfr[4];
#pragma unroll
    for (int m = 0; m < 4; ++m)
      af[m] = *(const bf16x8*)&As[cur][(wr * 64 + m * 16 + fr) * 32 + s0];
#pragma unroll
    for (int n = 0; n < 4; ++n)
      bfr[n] = *(const bf16x8*)&Bs[cur][(wc * 64 + n * 16 + fr) * 32 + s0];
#pragma unroll
    for (int m = 0; m < 4; ++m)
#pragma unroll
      for (int n = 0; n < 4; ++n)
        acc[m][n] = __builtin_amdgcn_mfma_f32_16x16x32_bf16(af[m], bfr[n], acc[m][n], 0, 0, 0);

    __builtin_amdgcn_s_barrier();
    cur += 1;
    if (cur >= 3) cur -= 3;
  }

  const int colBase = nblk * 128 + wc * 64 + (lane & 15);
  const int rowBase = mblk * 256 + wr * 64 + ((lane >> 4) << 2);
#pragma unroll
  for (int n = 0; n < 4; ++n) {
    const int c = colBase + n * 16;
    const float bv = bias[c];
#pragma unroll
    for (int m = 0; m < 4; ++m) {
#pragma unroll
      for (int j = 0; j < 4; ++j) {
        const int r = rowBase + m * 16 + j;
        if (r < Mloc) {
          Cbase[(size_t)(rowOff + r) * N + c] = (bf16_t)fmaxf(acc[m][n][j] + bv, 0.0f);
        }
      }
    }
  }
}

// ---------------- 128x128 BK=32 expert GEMM2, 4 waves (R15-proven, best of 4) ----
// A contiguous (mid + rowOff*K); bf16 out scattered to eout[entry] * wlist.
__global__ __launch_bounds__(256, 3) void k_gemm_e2(
    const bf16_t* __restrict__ Abase, const bf16_t* __restrict__ Bbase,
    const float* __restrict__ biasBase, bf16_t* __restrict__ Cbase,
    int N, int K,
    const int* __restrict__ cnt, const int* __restrict__ listBase,
    const float* __restrict__ wlistBase) {
  const int e = blockIdx.z;
  const int mblk = blockIdx.y, nblk = blockIdx.x;
  const int Mloc = cnt[e];
  if (mblk * 128 >= Mloc) return;  // uniform early exit, before any barrier
  int rowOff = 0;
  for (int i = 0; i < NEXP; ++i) rowOff += (i < e) ? cnt[i] : 0;
  const bf16_t* B = Bbase + (size_t)e * N * K;
  const float* bias = biasBase + (size_t)e * N;
  const int* myList = listBase + e * NTOK;
  const float* myW = wlistBase + e * NTOK;
  const bf16_t* A = Abase + (size_t)rowOff * K;

  __shared__ bf16_t As[3][128 * 32];
  __shared__ bf16_t Bs[3][128 * 32];

  const int tid = threadIdx.x;
  const int lane = tid & 63;
  const int wid = tid >> 6;
  const int wr = wid >> 1, wc = wid & 1;

  const int srow0 = wid * 32 + (lane >> 2);
  const int srow1 = srow0 + 16;
  const int skcol = ((lane & 3) ^ ((lane >> 3) & 3)) * 8;

  int ar0 = mblk * 128 + srow0;
  int ar1 = mblk * 128 + srow1;
  if (ar0 > Mloc - 1) ar0 = Mloc - 1;
  if (ar1 > Mloc - 1) ar1 = Mloc - 1;
  const bf16_t* aptr0 = A + (size_t)ar0 * K + skcol;
  const bf16_t* aptr1 = A + (size_t)ar1 * K + skcol;
  const bf16_t* bptr0 = B + (size_t)(nblk * 128 + srow0) * K + skcol;
  const bf16_t* bptr1 = B + (size_t)(nblk * 128 + srow1) * K + skcol;

  const int ldsOfsA0 = (wid * 32) * 32;
  const int ldsOfsA1 = (wid * 32 + 16) * 32;

  f32x4 acc[4][4] = {};
  const int nkt = K >> 5;

  auto stage = [&](int buf, int kt) {
    const size_t ko = (size_t)kt * 32;
    gload_lds16(aptr0 + ko, &As[buf][ldsOfsA0]);
    gload_lds16(aptr1 + ko, &As[buf][ldsOfsA1]);
    gload_lds16(bptr0 + ko, &Bs[buf][ldsOfsA0]);
    gload_lds16(bptr1 + ko, &Bs[buf][ldsOfsA1]);
  };

  stage(0, 0);
  if (nkt > 1) stage(1, 1);

  const int fr = lane & 15;
  const int s0 = (((lane >> 4) ^ ((fr >> 1) & 3)) << 3);

  int cur = 0;
  for (int kt = 0; kt < nkt; ++kt) {
    int nxt = cur + 2;
    if (nxt >= 3) nxt -= 3;
    if (kt + 2 < nkt) {
      stage(nxt, kt + 2);
      asm volatile("s_waitcnt vmcnt(8)" ::: "memory");
    } else if (kt + 1 < nkt) {
      asm volatile("s_waitcnt vmcnt(4)" ::: "memory");
    } else {
      asm volatile("s_waitcnt vmcnt(0)" ::: "memory");
    }
    __builtin_amdgcn_s_barrier();

    bf16x8 af[4], bfr[4];
#pragma unroll
    for (int m = 0; m < 4; ++m)
      af[m] = *(const bf16x8*)&As[cur][(wr * 64 + m * 16 + fr) * 32 + s0];
#pragma unroll
    for (int n = 0; n < 4; ++n)
      bfr[n] = *(const bf16x8*)&Bs[cur][(wc * 64 + n * 16 + fr) * 32 + s0];
#pragma unroll
    for (int m = 0; m < 4; ++m)
#pragma unroll
      for (int n = 0; n < 4; ++n)
        acc[m][n] = __builtin_amdgcn_mfma_f32_16x16x32_bf16(af[m], bfr[n], acc[m][n], 0, 0, 0);

    __builtin_amdgcn_s_barrier();
    cur += 1;
    if (cur >= 3) cur -= 3;
  }

  const int colBase = nblk * 128 + wc * 64 + (lane & 15);
  const int rowBase = mblk * 128 + wr * 64 + ((lane >> 4) << 2);
#pragma unroll
  for (int n = 0; n < 4; ++n) {
    const int c = colBase + n * 16;
    const float bv = bias[c];
#pragma unroll
    for (int m = 0; m < 4; ++m) {
#pragma unroll
      for (int j = 0; j < 4; ++j) {
        const int r = rowBase + m * 16 + j;
        if (r < Mloc) {
          const int entry = myList[r];
          const float w = myW[r];
          Cbase[(size_t)entry * DH + c] = (bf16_t)((acc[m][n][j] + bv) * w);
        }
      }
    }
  }
}

// ---------------- launch ----------------

extern "C" void kernel_launch(void* const* d_in, const int* in_sizes, int n_in,
                              void* d_out, int out_size, void* d_ws, size_t ws_size,
                              hipStream_t stream) {
  const float* x      = (const float*)d_in[0];
  const float* W_in   = (const float*)d_in[1];
  const float* b_in   = (const float*)d_in[2];
  const float* W_gate = (const float*)d_in[3];
  const float* b_gate = (const float*)d_in[4];
  const float* W1     = (const float*)d_in[5];
  const float* b1     = (const float*)d_in[6];
  const float* W2     = (const float*)d_in[7];
  const float* b2     = (const float*)d_in[8];
  const float* W_out  = (const float*)d_in[9];
  const float* b_out  = (const float*)d_in[10];

  char* ws = (char*)d_ws;
  size_t off = 0;
  auto alloc = [&](size_t bytes) -> void* {
    void* p = ws + off;
    off += (bytes + 255) & ~(size_t)255;
    return p;
  };

  bf16_t* WtIn  = (bf16_t*)alloc((size_t)DH * DIN * 2);
  bf16_t* Wt1   = (bf16_t*)alloc((size_t)NEXP * DMOE * DH * 2);
  bf16_t* Wt2   = (bf16_t*)alloc((size_t)NEXP * DH * DMOE * 2);
  bf16_t* WtOut = (bf16_t*)alloc((size_t)DH * DH * 2);
  bf16_t* xbf   = (bf16_t*)alloc((size_t)NTOK * DIN * 2);
  bf16_t* hbf   = (bf16_t*)alloc((size_t)NTOK * DH * 2);
  bf16_t* mid   = (bf16_t*)alloc((size_t)2 * NTOK * DMOE * 2);
  bf16_t* eoutb = (bf16_t*)alloc((size_t)2 * NTOK * DH * 2);
  bf16_t* moebf = (bf16_t*)alloc((size_t)NTOK * DH * 2);
  double* G     = (double*)alloc((size_t)DIN * 8 * 8);
  double* cvec  = (double*)alloc(8 * 8);
  int*    cnt   = (int*)alloc(NEXP * 4);
  int*    list  = (int*)alloc((size_t)NEXP * NTOK * 4);
  float*  wlist = (float*)alloc((size_t)NEXP * NTOK * 4);

  k_transpose_all<<<20992, 256, 0, stream>>>(W_in, W1, W2, W_out, x,
                                             WtIn, Wt1, Wt2, WtOut, xbf);

  k_gate_prep<<<64, 256, 0, stream>>>(W_in, W_gate, b_in, b_gate, G, cvec, cnt);
  k_gating<<<NTOK / 4, 256, 0, stream>>>(x, G, cvec, cnt, list, wlist);

  // h = x @ W_in + b_in  (bf16 out)
  k_gemm_plain<0><<<dim3(DH / 128, NTOK / 128, 1), 256, 0, stream>>>(
      xbf, WtIn, b_in, hbf, NTOK, DH, DIN);
  // mid = relu(h_gathered @ W1[e] + b1[e])  (256x128, 8 waves)
  k_gemm1<<<dim3(DMOE / 128, NTOK / 256, NEXP), 512, 0, stream>>>(
      hbf, Wt1, b1, mid, DMOE, DH, cnt, list);
  // eout[entry] = bf16((mid @ W2[e] + b2[e]) * route_w)  (128^2, best-measured)
  k_gemm_e2<<<dim3(DH / 128, NTOK / 128, NEXP), 256, 0, stream>>>(
      mid, Wt2, b2, eoutb, DH, DMOE, cnt, list, wlist);
  k_combine<<<NTOK * DH / 4 / 256, 256, 0, stream>>>(eoutb, moebf);
  // out = moe @ W_out + b_out (fp32 out)
  k_gemm_plain<1><<<dim3(DH / 128, NTOK / 128, 1), 256, 0, stream>>>(
      moebf, WtOut, b_out, (float*)d_out, NTOK, DH, DH);
}

// Round 20
// 528.531 us; speedup vs baseline: 1.1023x; 1.0530x over previous
//
#include <hip/hip_runtime.h>
#include <hip/hip_bf16.h>

typedef __bf16 bf16_t;
typedef bf16_t bf16x8 __attribute__((ext_vector_type(8)));
typedef bf16_t bf16x4 __attribute__((ext_vector_type(4)));
typedef float f32x4 __attribute__((ext_vector_type(4)));

#define DIN 1024
#define DH 1024
#define DMOE 4096
#define NEXP 8
#define NTOK 4096

__device__ __forceinline__ void gload_lds16(const bf16_t* g, bf16_t* l) {
  __builtin_amdgcn_global_load_lds(
      (const __attribute__((address_space(1))) void*)g,
      (__attribute__((address_space(3))) void*)l, 16, 0, 0);
}

// ---------------- unified prep: 4 weight transposes + x cvt + fp64 gate-prep ------
// z in [0,256) WtIn, [256,8448) W1, [8448,16640) W2, [16640,16896) WtOut,
// [16896,20992) x->bf16 cvt, [20992,21056) gate_prep (G = W_in@W_gate fp64, cvec, cnt=0).
__global__ void k_prep_all(const float* __restrict__ W_in, const float* __restrict__ W1,
                           const float* __restrict__ W2, const float* __restrict__ W_out,
                           const float* __restrict__ x,
                           const float* __restrict__ Wgate, const float* __restrict__ b_in,
                           const float* __restrict__ b_gate,
                           bf16_t* __restrict__ WtIn, bf16_t* __restrict__ Wt1,
                           bf16_t* __restrict__ Wt2, bf16_t* __restrict__ WtOut,
                           bf16_t* __restrict__ xbf,
                           double* __restrict__ G, double* __restrict__ cvec,
                           int* __restrict__ cnt) {
  const int z = blockIdx.x;
  if (z >= 20992) {
    // ---- gate_prep slice: 64 blocks x 4 waves = 256 waves over d in [0, DIN] ----
    const int b = z - 20992;
    if (b == 0 && threadIdx.x < 8) cnt[threadIdx.x] = 0;
    const int lane = threadIdx.x & 63;
    const int wave = b * 4 + (threadIdx.x >> 6);
    const int nw = 256;
    for (int d = wave; d <= DIN; d += nw) {
      const float* row = (d < DIN) ? (W_in + (size_t)d * DH) : b_in;
      double acc[8] = {0, 0, 0, 0, 0, 0, 0, 0};
      for (int k = lane; k < DH; k += 64) {
        const double xv = (double)row[k];
        const float* g = Wgate + (size_t)k * NEXP;
#pragma unroll
        for (int ee = 0; ee < 8; ++ee) acc[ee] += xv * (double)g[ee];
      }
#pragma unroll
      for (int ee = 0; ee < 8; ++ee) {
        double a = acc[ee];
        for (int o = 32; o > 0; o >>= 1) a += __shfl_down(a, o);
        acc[ee] = a;
      }
      if (lane == 0) {
        if (d < DIN) {
#pragma unroll
          for (int ee = 0; ee < 8; ++ee) G[(size_t)d * 8 + ee] = acc[ee];
        } else {
#pragma unroll
          for (int ee = 0; ee < 8; ++ee) cvec[ee] = acc[ee] + (double)b_gate[ee];
        }
      }
    }
    return;
  }
  if (z >= 16896) {
    const int i = (z - 16896) * 256 + threadIdx.x;
    const float4 v = *(const float4*)(x + (size_t)i * 4);
    bf16x4 o;
    o.x = (bf16_t)v.x; o.y = (bf16_t)v.y; o.z = (bf16_t)v.z; o.w = (bf16_t)v.w;
    *(bf16x4*)(xbf + (size_t)i * 4) = o;
    return;
  }
  const float* s; bf16_t* d; int R, C, tx, ty;
  if (z < 256) {
    s = W_in; d = WtIn; R = DIN; C = DH; tx = z & 15; ty = z >> 4;
  } else if (z < 8448) {
    const int l = z - 256, e = l >> 10, t = l & 1023;
    s = W1 + (size_t)e * DH * DMOE; d = Wt1 + (size_t)e * DH * DMOE;
    R = DH; C = DMOE; tx = t & 63; ty = t >> 6;
  } else if (z < 16640) {
    const int l = z - 8448, e = l >> 10, t = l & 1023;
    s = W2 + (size_t)e * DMOE * DH; d = Wt2 + (size_t)e * DMOE * DH;
    R = DMOE; C = DH; tx = t & 15; ty = t >> 4;
  } else {
    const int t = z - 16640;
    s = W_out; d = WtOut; R = DH; C = DH; tx = t & 15; ty = t >> 4;
  }
  __shared__ float tile[64][65];
  const int c0 = tx * 64, r0 = ty * 64;
  const int t = threadIdx.x;
  const int rr = t >> 4;
  const int cc = (t & 15) << 2;
#pragma unroll
  for (int i = 0; i < 64; i += 16) {
    const float4 v = *(const float4*)&s[(size_t)(r0 + rr + i) * C + c0 + cc];
    tile[rr + i][cc + 0] = v.x;
    tile[rr + i][cc + 1] = v.y;
    tile[rr + i][cc + 2] = v.z;
    tile[rr + i][cc + 3] = v.w;
  }
  __syncthreads();
  const int orr = (t & 7) * 8;
  const int oc = t >> 3;
#pragma unroll
  for (int i = 0; i < 64; i += 32) {
    bf16x8 o;
#pragma unroll
    for (int j = 0; j < 8; ++j) o[j] = (bf16_t)tile[orr + j][oc + i];
    *(bf16x8*)&d[(size_t)(c0 + oc + i) * R + r0 + orr] = o;
  }
}

// moe_bf16[t] = bf16(eout[t][0] + eout[t][1])
__global__ void k_combine(const bf16_t* __restrict__ eout, bf16_t* __restrict__ moebf) {
  const int i = blockIdx.x * blockDim.x + threadIdx.x;
  const int t = i >> 8;
  const int q = (i & 255) * 4;
  const bf16x4 a = *(const bf16x4*)(eout + ((size_t)t * 2) * DH + q);
  const bf16x4 b = *(const bf16x4*)(eout + ((size_t)t * 2 + 1) * DH + q);
  bf16x4 o;
  o.x = (bf16_t)((float)a.x + (float)b.x);
  o.y = (bf16_t)((float)a.y + (float)b.y);
  o.z = (bf16_t)((float)a.z + (float)b.z);
  o.w = (bf16_t)((float)a.w + (float)b.w);
  *(bf16x4*)(moebf + (size_t)t * DH + q) = o;
}

// ---------------- fused GEMM0 (h = x@W_in + b_in) + gating, one launch ----------
// grid dim3(8,32,5): z==0 -> 128x128 GEMM0 tile (R10 structure); z in [1,5) ->
// gating blocks (4 waves x 1 token), backfilling GEMM0's idle CU slots.
__global__ __launch_bounds__(256, 3) void k_gemm0_gating(
    const bf16_t* __restrict__ A, const bf16_t* __restrict__ B,
    const float* __restrict__ bias, bf16_t* __restrict__ Cbase,
    const float* __restrict__ x, const double* __restrict__ G,
    const double* __restrict__ cvec, int* __restrict__ cnt,
    int* __restrict__ list, float* __restrict__ wlist) {
  constexpr int M = NTOK, N = DH, K = DIN;
  if (blockIdx.z > 0) {
    // ---- gating: token t, fp64 logits via fused G, softmax, top-2, scatter ----
    const int lane = threadIdx.x & 63;
    const int bl = (blockIdx.z - 1) * 256 + blockIdx.y * 8 + blockIdx.x;
    const int t = bl * 4 + (threadIdx.x >> 6);
    const float* xr = x + (size_t)t * DIN;
    double acc[8] = {0, 0, 0, 0, 0, 0, 0, 0};
    for (int d = lane; d < DIN; d += 64) {
      const double xv = (double)xr[d];
      const double* g = G + (size_t)d * 8;
#pragma unroll
      for (int ee = 0; ee < 8; ++ee) acc[ee] += xv * g[ee];
    }
#pragma unroll
    for (int ee = 0; ee < 8; ++ee) {
      double a = acc[ee];
      for (int o = 32; o > 0; o >>= 1) a += __shfl_down(a, o);
      acc[ee] = a;
    }
    if (lane == 0) {
      double l[8];
#pragma unroll
      for (int ee = 0; ee < 8; ++ee) l[ee] = acc[ee] + cvec[ee];
      double m = l[0];
#pragma unroll
      for (int ee = 1; ee < 8; ++ee) m = fmax(m, l[ee]);
      double p[8];
#pragma unroll
      for (int ee = 0; ee < 8; ++ee) p[ee] = exp(l[ee] - m);
      int i1 = 0;
#pragma unroll
      for (int ee = 1; ee < 8; ++ee)
        if (p[ee] > p[i1]) i1 = ee;
      int i2 = (i1 == 0) ? 1 : 0;
#pragma unroll
      for (int ee = 0; ee < 8; ++ee)
        if (ee != i1 && p[ee] > p[i2]) i2 = ee;
      const double s2 = p[i1] + p[i2];
      const float w1 = (float)(p[i1] / s2);
      const float w2 = (float)(p[i2] / s2);
      int lp = atomicAdd(&cnt[i1], 1);
      list[i1 * NTOK + lp] = t * 2;
      wlist[i1 * NTOK + lp] = w1;
      lp = atomicAdd(&cnt[i2], 1);
      list[i2 * NTOK + lp] = t * 2 + 1;
      wlist[i2 * NTOK + lp] = w2;
    }
    return;
  }

  // ---- GEMM0: 128x128 BK=32, 4 waves, 3-buf depth-2 counted vmcnt, swizzled ----
  const int mblk = blockIdx.y, nblk = blockIdx.x;

  __shared__ bf16_t As[3][128 * 32];
  __shared__ bf16_t Bs[3][128 * 32];

  const int tid = threadIdx.x;
  const int lane = tid & 63;
  const int wid = tid >> 6;
  const int wr = wid >> 1, wc = wid & 1;

  const int srow0 = wid * 32 + (lane >> 2);
  const int srow1 = srow0 + 16;
  const int skcol = ((lane & 3) ^ ((lane >> 3) & 3)) * 8;

  const bf16_t* aptr0 = A + (size_t)(mblk * 128 + srow0) * K + skcol;
  const bf16_t* aptr1 = A + (size_t)(mblk * 128 + srow1) * K + skcol;
  const bf16_t* bptr0 = B + (size_t)(nblk * 128 + srow0) * K + skcol;
  const bf16_t* bptr1 = B + (size_t)(nblk * 128 + srow1) * K + skcol;

  const int ldsOfsA0 = (wid * 32) * 32;
  const int ldsOfsA1 = (wid * 32 + 16) * 32;

  f32x4 acc[4][4] = {};
  const int nkt = K >> 5;

  auto stage = [&](int buf, int kt) {
    const size_t ko = (size_t)kt * 32;
    gload_lds16(aptr0 + ko, &As[buf][ldsOfsA0]);
    gload_lds16(aptr1 + ko, &As[buf][ldsOfsA1]);
    gload_lds16(bptr0 + ko, &Bs[buf][ldsOfsA0]);
    gload_lds16(bptr1 + ko, &Bs[buf][ldsOfsA1]);
  };

  stage(0, 0);
  if (nkt > 1) stage(1, 1);

  const int fr = lane & 15;
  const int s0 = (((lane >> 4) ^ ((fr >> 1) & 3)) << 3);

  int cur = 0;
  for (int kt = 0; kt < nkt; ++kt) {
    int nxt = cur + 2;
    if (nxt >= 3) nxt -= 3;
    if (kt + 2 < nkt) {
      stage(nxt, kt + 2);
      asm volatile("s_waitcnt vmcnt(8)" ::: "memory");
    } else if (kt + 1 < nkt) {
      asm volatile("s_waitcnt vmcnt(4)" ::: "memory");
    } else {
      asm volatile("s_waitcnt vmcnt(0)" ::: "memory");
    }
    __builtin_amdgcn_s_barrier();

    bf16x8 af[4], bfr[4];
#pragma unroll
    for (int m = 0; m < 4; ++m)
      af[m] = *(const bf16x8*)&As[cur][(wr * 64 + m * 16 + fr) * 32 + s0];
#pragma unroll
    for (int n = 0; n < 4; ++n)
      bfr[n] = *(const bf16x8*)&Bs[cur][(wc * 64 + n * 16 + fr) * 32 + s0];
#pragma unroll
    for (int m = 0; m < 4; ++m)
#pragma unroll
      for (int n = 0; n < 4; ++n)
        acc[m][n] = __builtin_amdgcn_mfma_f32_16x16x32_bf16(af[m], bfr[n], acc[m][n], 0, 0, 0);

    __builtin_amdgcn_s_barrier();
    cur += 1;
    if (cur >= 3) cur -= 3;
  }

  const int colBase = nblk * 128 + wc * 64 + (lane & 15);
  const int rowBase = mblk * 128 + wr * 64 + ((lane >> 4) << 2);
#pragma unroll
  for (int n = 0; n < 4; ++n) {
    const int c = colBase + n * 16;
    const float bv = bias[c];
#pragma unroll
    for (int m = 0; m < 4; ++m) {
#pragma unroll
      for (int j = 0; j < 4; ++j) {
        const int r = rowBase + m * 16 + j;
        Cbase[(size_t)r * N + c] = (bf16_t)(acc[m][n][j] + bv);
      }
    }
  }
}

// ---------------- 128x128 BK=32 plain GEMM, 4 waves (GEMM3, fp32 out) ----------
__global__ __launch_bounds__(256, 3) void k_gemm_out(
    const bf16_t* __restrict__ A, const bf16_t* __restrict__ B,
    const float* __restrict__ bias, float* __restrict__ Cbase,
    int M, int N, int K) {
  const int mblk = blockIdx.y, nblk = blockIdx.x;

  __shared__ bf16_t As[3][128 * 32];
  __shared__ bf16_t Bs[3][128 * 32];

  const int tid = threadIdx.x;
  const int lane = tid & 63;
  const int wid = tid >> 6;
  const int wr = wid >> 1, wc = wid & 1;

  const int srow0 = wid * 32 + (lane >> 2);
  const int srow1 = srow0 + 16;
  const int skcol = ((lane & 3) ^ ((lane >> 3) & 3)) * 8;

  const bf16_t* aptr0 = A + (size_t)(mblk * 128 + srow0) * K + skcol;
  const bf16_t* aptr1 = A + (size_t)(mblk * 128 + srow1) * K + skcol;
  const bf16_t* bptr0 = B + (size_t)(nblk * 128 + srow0) * K + skcol;
  const bf16_t* bptr1 = B + (size_t)(nblk * 128 + srow1) * K + skcol;

  const int ldsOfsA0 = (wid * 32) * 32;
  const int ldsOfsA1 = (wid * 32 + 16) * 32;

  f32x4 acc[4][4] = {};
  const int nkt = K >> 5;

  auto stage = [&](int buf, int kt) {
    const size_t ko = (size_t)kt * 32;
    gload_lds16(aptr0 + ko, &As[buf][ldsOfsA0]);
    gload_lds16(aptr1 + ko, &As[buf][ldsOfsA1]);
    gload_lds16(bptr0 + ko, &Bs[buf][ldsOfsA0]);
    gload_lds16(bptr1 + ko, &Bs[buf][ldsOfsA1]);
  };

  stage(0, 0);
  if (nkt > 1) stage(1, 1);

  const int fr = lane & 15;
  const int s0 = (((lane >> 4) ^ ((fr >> 1) & 3)) << 3);

  int cur = 0;
  for (int kt = 0; kt < nkt; ++kt) {
    int nxt = cur + 2;
    if (nxt >= 3) nxt -= 3;
    if (kt + 2 < nkt) {
      stage(nxt, kt + 2);
      asm volatile("s_waitcnt vmcnt(8)" ::: "memory");
    } else if (kt + 1 < nkt) {
      asm volatile("s_waitcnt vmcnt(4)" ::: "memory");
    } else {
      asm volatile("s_waitcnt vmcnt(0)" ::: "memory");
    }
    __builtin_amdgcn_s_barrier();

    bf16x8 af[4], bfr[4];
#pragma unroll
    for (int m = 0; m < 4; ++m)
      af[m] = *(const bf16x8*)&As[cur][(wr * 64 + m * 16 + fr) * 32 + s0];
#pragma unroll
    for (int n = 0; n < 4; ++n)
      bfr[n] = *(const bf16x8*)&Bs[cur][(wc * 64 + n * 16 + fr) * 32 + s0];
#pragma unroll
    for (int m = 0; m < 4; ++m)
#pragma unroll
      for (int n = 0; n < 4; ++n)
        acc[m][n] = __builtin_amdgcn_mfma_f32_16x16x32_bf16(af[m], bfr[n], acc[m][n], 0, 0, 0);

    __builtin_amdgcn_s_barrier();
    cur += 1;
    if (cur >= 3) cur -= 3;
  }

  const int colBase = nblk * 128 + wc * 64 + (lane & 15);
  const int rowBase = mblk * 128 + wr * 64 + ((lane >> 4) << 2);
#pragma unroll
  for (int n = 0; n < 4; ++n) {
    const int c = colBase + n * 16;
    const float bv = bias[c];
#pragma unroll
    for (int m = 0; m < 4; ++m) {
#pragma unroll
      for (int j = 0; j < 4; ++j) {
        const int r = rowBase + m * 16 + j;
        Cbase[(size_t)r * N + c] = acc[m][n][j] + bv;
      }
    }
  }
}

// ---------------- 256x128 BK=32 expert GEMM1, 8 waves (R15-proven) ------
__global__ __launch_bounds__(512, 4) void k_gemm1(
    const bf16_t* __restrict__ Abase, const bf16_t* __restrict__ Bbase,
    const float* __restrict__ biasBase, bf16_t* __restrict__ Cbase,
    int N, int K,
    const int* __restrict__ cnt, const int* __restrict__ listBase) {
  const int e = blockIdx.z;
  const int mblk = blockIdx.y, nblk = blockIdx.x;
  const int Mloc = cnt[e];
  if (mblk * 256 >= Mloc) return;
  int rowOff = 0;
  for (int i = 0; i < NEXP; ++i) rowOff += (i < e) ? cnt[i] : 0;
  const bf16_t* B = Bbase + (size_t)e * N * K;
  const float* bias = biasBase + (size_t)e * N;
  const int* myList = listBase + e * NTOK;

  __shared__ bf16_t As[3][256 * 32];
  __shared__ bf16_t Bs[3][128 * 32];

  const int tid = threadIdx.x;
  const int lane = tid & 63;
  const int wid = tid >> 6;
  const int wr = wid >> 1, wc = wid & 1;

  const int subr = lane >> 2;
  const int skcol = ((lane & 3) ^ ((lane >> 3) & 3)) * 8;

  uint32_t aofs[2];
#pragma unroll
  for (int l = 0; l < 2; ++l) {
    int ar = mblk * 256 + (wid * 2 + l) * 16 + subr;
    if (ar > Mloc - 1) ar = Mloc - 1;
    aofs[l] = (uint32_t)(myList[ar] >> 1) * (uint32_t)K + skcol;
  }
  const uint32_t bofs = (uint32_t)(nblk * 128 + wid * 16 + subr) * (uint32_t)K + skcol;

  f32x4 acc[4][4] = {};
  const int nkt = K >> 5;

  auto stage = [&](int buf, int kt) {
    const uint32_t ko = (uint32_t)kt * 32;
    gload_lds16(Abase + aofs[0] + ko, &As[buf][(wid * 2 + 0) * 512]);
    gload_lds16(Abase + aofs[1] + ko, &As[buf][(wid * 2 + 1) * 512]);
    gload_lds16(B + bofs + ko, &Bs[buf][wid * 512]);
  };

  stage(0, 0);
  if (nkt > 1) stage(1, 1);

  const int fr = lane & 15;
  const int s0 = (((lane >> 4) ^ ((fr >> 1) & 3)) << 3);

  int cur = 0;
  for (int kt = 0; kt < nkt; ++kt) {
    int nxt = cur + 2;
    if (nxt >= 3) nxt -= 3;
    if (kt + 2 < nkt) {
      stage(nxt, kt + 2);
      asm volatile("s_waitcnt vmcnt(6)" ::: "memory");
    } else if (kt + 1 < nkt) {
      asm volatile("s_waitcnt vmcnt(3)" ::: "memory");
    } else {
      asm volatile("s_waitcnt vmcnt(0)" ::: "memory");
    }
    __builtin_amdgcn_s_barrier();

    bf16x8 af[4], bfr[4];
#pragma unroll
    for (int m = 0; m < 4; ++m)
      af[m] = *(const bf16x8*)&As[cur][(wr * 64 + m * 16 + fr) * 32 + s0];
#pragma unroll
    for (int n = 0; n < 4; ++n)
      bfr[n] = *(const bf16x8*)&Bs[cur][(wc * 64 + n * 16 + fr) * 32 + s0];
#pragma unroll
    for (int m = 0; m < 4; ++m)
#pragma unroll
      for (int n = 0; n < 4; ++n)
        acc[m][n] = __builtin_amdgcn_mfma_f32_16x16x32_bf16(af[m], bfr[n], acc[m][n], 0, 0, 0);

    __builtin_amdgcn_s_barrier();
    cur += 1;
    if (cur >= 3) cur -= 3;
  }

  const int colBase = nblk * 128 + wc * 64 + (lane & 15);
  const int rowBase = mblk * 256 + wr * 64 + ((lane >> 4) << 2);
#pragma unroll
  for (int n = 0; n < 4; ++n) {
    const int c = colBase + n * 16;
    const float bv = bias[c];
#pragma unroll
    for (int m = 0; m < 4; ++m) {
#pragma unroll
      for (int j = 0; j < 4; ++j) {
        const int r = rowBase + m * 16 + j;
        if (r < Mloc) {
          Cbase[(size_t)(rowOff + r) * N + c] = (bf16_t)fmaxf(acc[m][n][j] + bv, 0.0f);
        }
      }
    }
  }
}

// ---------------- 128x128 BK=32 expert GEMM2, 4 waves (R15-proven, best of 4) ----
__global__ __launch_bounds__(256, 3) void k_gemm_e2(
    const bf16_t* __restrict__ Abase, const bf16_t* __restrict__ Bbase,
    const float* __restrict__ biasBase, bf16_t* __restrict__ Cbase,
    int N, int K,
    const int* __restrict__ cnt, const int* __restrict__ listBase,
    const float* __restrict__ wlistBase) {
  const int e = blockIdx.z;
  const int mblk = blockIdx.y, nblk = blockIdx.x;
  const int Mloc = cnt[e];
  if (mblk * 128 >= Mloc) return;
  int rowOff = 0;
  for (int i = 0; i < NEXP; ++i) rowOff += (i < e) ? cnt[i] : 0;
  const bf16_t* B = Bbase + (size_t)e * N * K;
  const float* bias = biasBase + (size_t)e * N;
  const int* myList = listBase + e * NTOK;
  const float* myW = wlistBase + e * NTOK;
  const bf16_t* A = Abase + (size_t)rowOff * K;

  __shared__ bf16_t As[3][128 * 32];
  __shared__ bf16_t Bs[3][128 * 32];

  const int tid = threadIdx.x;
  const int lane = tid & 63;
  const int wid = tid >> 6;
  const int wr = wid >> 1, wc = wid & 1;

  const int srow0 = wid * 32 + (lane >> 2);
  const int srow1 = srow0 + 16;
  const int skcol = ((lane & 3) ^ ((lane >> 3) & 3)) * 8;

  int ar0 = mblk * 128 + srow0;
  int ar1 = mblk * 128 + srow1;
  if (ar0 > Mloc - 1) ar0 = Mloc - 1;
  if (ar1 > Mloc - 1) ar1 = Mloc - 1;
  const bf16_t* aptr0 = A + (size_t)ar0 * K + skcol;
  const bf16_t* aptr1 = A + (size_t)ar1 * K + skcol;
  const bf16_t* bptr0 = B + (size_t)(nblk * 128 + srow0) * K + skcol;
  const bf16_t* bptr1 = B + (size_t)(nblk * 128 + srow1) * K + skcol;

  const int ldsOfsA0 = (wid * 32) * 32;
  const int ldsOfsA1 = (wid * 32 + 16) * 32;

  f32x4 acc[4][4] = {};
  const int nkt = K >> 5;

  auto stage = [&](int buf, int kt) {
    const size_t ko = (size_t)kt * 32;
    gload_lds16(aptr0 + ko, &As[buf][ldsOfsA0]);
    gload_lds16(aptr1 + ko, &As[buf][ldsOfsA1]);
    gload_lds16(bptr0 + ko, &Bs[buf][ldsOfsA0]);
    gload_lds16(bptr1 + ko, &Bs[buf][ldsOfsA1]);
  };

  stage(0, 0);
  if (nkt > 1) stage(1, 1);

  const int fr = lane & 15;
  const int s0 = (((lane >> 4) ^ ((fr >> 1) & 3)) << 3);

  int cur = 0;
  for (int kt = 0; kt < nkt; ++kt) {
    int nxt = cur + 2;
    if (nxt >= 3) nxt -= 3;
    if (kt + 2 < nkt) {
      stage(nxt, kt + 2);
      asm volatile("s_waitcnt vmcnt(8)" ::: "memory");
    } else if (kt + 1 < nkt) {
      asm volatile("s_waitcnt vmcnt(4)" ::: "memory");
    } else {
      asm volatile("s_waitcnt vmcnt(0)" ::: "memory");
    }
    __builtin_amdgcn_s_barrier();

    bf16x8 af[4], bfr[4];
#pragma unroll
    for (int m = 0; m < 4; ++m)
      af[m] = *(const bf16x8*)&As[cur][(wr * 64 + m * 16 + fr) * 32 + s0];
#pragma unroll
    for (int n = 0; n < 4; ++n)
      bfr[n] = *(const bf16x8*)&Bs[cur][(wc * 64 + n * 16 + fr) * 32 + s0];
#pragma unroll
    for (int m = 0; m < 4; ++m)
#pragma unroll
      for (int n = 0; n < 4; ++n)
        acc[m][n] = __builtin_amdgcn_mfma_f32_16x16x32_bf16(af[m], bfr[n], acc[m][n], 0, 0, 0);

    __builtin_amdgcn_s_barrier();
    cur += 1;
    if (cur >= 3) cur -= 3;
  }

  const int colBase = nblk * 128 + wc * 64 + (lane & 15);
  const int rowBase = mblk * 128 + wr * 64 + ((lane >> 4) << 2);
#pragma unroll
  for (int n = 0; n < 4; ++n) {
    const int c = colBase + n * 16;
    const float bv = bias[c];
#pragma unroll
    for (int m = 0; m < 4; ++m) {
#pragma unroll
      for (int j = 0; j < 4; ++j) {
        const int r = rowBase + m * 16 + j;
        if (r < Mloc) {
          const int entry = myList[r];
          const float w = myW[r];
          Cbase[(size_t)entry * DH + c] = (bf16_t)((acc[m][n][j] + bv) * w);
        }
      }
    }
  }
}

// ---------------- launch ----------------

extern "C" void kernel_launch(void* const* d_in, const int* in_sizes, int n_in,
                              void* d_out, int out_size, void* d_ws, size_t ws_size,
                              hipStream_t stream) {
  const float* x      = (const float*)d_in[0];
  const float* W_in   = (const float*)d_in[1];
  const float* b_in   = (const float*)d_in[2];
  const float* W_gate = (const float*)d_in[3];
  const float* b_gate = (const float*)d_in[4];
  const float* W1     = (const float*)d_in[5];
  const float* b1     = (const float*)d_in[6];
  const float* W2     = (const float*)d_in[7];
  const float* b2     = (const float*)d_in[8];
  const float* W_out  = (const float*)d_in[9];
  const float* b_out  = (const float*)d_in[10];

  char* ws = (char*)d_ws;
  size_t off = 0;
  auto alloc = [&](size_t bytes) -> void* {
    void* p = ws + off;
    off += (bytes + 255) & ~(size_t)255;
    return p;
  };

  bf16_t* WtIn  = (bf16_t*)alloc((size_t)DH * DIN * 2);
  bf16_t* Wt1   = (bf16_t*)alloc((size_t)NEXP * DMOE * DH * 2);
  bf16_t* Wt2   = (bf16_t*)alloc((size_t)NEXP * DH * DMOE * 2);
  bf16_t* WtOut = (bf16_t*)alloc((size_t)DH * DH * 2);
  bf16_t* xbf   = (bf16_t*)alloc((size_t)NTOK * DIN * 2);
  bf16_t* hbf   = (bf16_t*)alloc((size_t)NTOK * DH * 2);
  bf16_t* mid   = (bf16_t*)alloc((size_t)2 * NTOK * DMOE * 2);
  bf16_t* eoutb = (bf16_t*)alloc((size_t)2 * NTOK * DH * 2);
  bf16_t* moebf = (bf16_t*)alloc((size_t)NTOK * DH * 2);
  double* G     = (double*)alloc((size_t)DIN * 8 * 8);
  double* cvec  = (double*)alloc(8 * 8);
  int*    cnt   = (int*)alloc(NEXP * 4);
  int*    list  = (int*)alloc((size_t)NEXP * NTOK * 4);
  float*  wlist = (float*)alloc((size_t)NEXP * NTOK * 4);

  // prep: 4 weight transposes + x cvt + fp64 gate-prep (cnt zeroed), one launch
  k_prep_all<<<21056, 256, 0, stream>>>(W_in, W1, W2, W_out, x, W_gate, b_in, b_gate,
                                        WtIn, Wt1, Wt2, WtOut, xbf, G, cvec, cnt);

  // fused: h = x @ W_in + b_in  (z=0 tiles)  ∥  gating (z=1..4 backfill)
  k_gemm0_gating<<<dim3(DH / 128, NTOK / 128, 5), 256, 0, stream>>>(
      xbf, WtIn, b_in, hbf, x, G, cvec, cnt, list, wlist);

  // mid = relu(h_gathered @ W1[e] + b1[e])  (256x128, 8 waves)
  k_gemm1<<<dim3(DMOE / 128, NTOK / 256, NEXP), 512, 0, stream>>>(
      hbf, Wt1, b1, mid, DMOE, DH, cnt, list);
  // eout[entry] = bf16((mid @ W2[e] + b2[e]) * route_w)  (128^2, best-measured)
  k_gemm_e2<<<dim3(DH / 128, NTOK / 128, NEXP), 256, 0, stream>>>(
      mid, Wt2, b2, eoutb, DH, DMOE, cnt, list, wlist);
  k_combine<<<NTOK * DH / 4 / 256, 256, 0, stream>>>(eoutb, moebf);
  // out = moe @ W_out + b_out (fp32 out)
  k_gemm_out<<<dim3(DH / 128, NTOK / 128, 1), 256, 0, stream>>>(
      moebf, WtOut, b_out, (float*)d_out, NTOK, DH, DH);
}

// Round 21
// 514.478 us; speedup vs baseline: 1.1325x; 1.0273x over previous
//
#include <hip/hip_runtime.h>
#include <hip/hip_bf16.h>

typedef __bf16 bf16_t;
typedef bf16_t bf16x8 __attribute__((ext_vector_type(8)));
typedef bf16_t bf16x4 __attribute__((ext_vector_type(4)));
typedef float f32x4 __attribute__((ext_vector_type(4)));

#define DIN 1024
#define DH 1024
#define DMOE 4096
#define NEXP 8
#define NTOK 4096

__device__ __forceinline__ void gload_lds16(const bf16_t* g, bf16_t* l) {
  __builtin_amdgcn_global_load_lds(
      (const __attribute__((address_space(1))) void*)g,
      (__attribute__((address_space(3))) void*)l, 16, 0, 0);
}

// 64x64 transpose+cvt tile body (R14-proven).  smem must be >= 64*65*4 bytes.
__device__ __forceinline__ void transpose_tile(const float* __restrict__ s,
                                               bf16_t* __restrict__ d, int R, int C,
                                               int tx, int ty, void* smem) {
  float (*tile)[65] = (float(*)[65])smem;
  const int c0 = tx * 64, r0 = ty * 64;
  const int t = threadIdx.x;
  const int rr = t >> 4;
  const int cc = (t & 15) << 2;
#pragma unroll
  for (int i = 0; i < 64; i += 16) {
    const float4 v = *(const float4*)&s[(size_t)(r0 + rr + i) * C + c0 + cc];
    tile[rr + i][cc + 0] = v.x;
    tile[rr + i][cc + 1] = v.y;
    tile[rr + i][cc + 2] = v.z;
    tile[rr + i][cc + 3] = v.w;
  }
  __syncthreads();
  const int orr = (t & 7) * 8;
  const int oc = t >> 3;
#pragma unroll
  for (int i = 0; i < 64; i += 32) {
    bf16x8 o;
#pragma unroll
    for (int j = 0; j < 8; ++j) o[j] = (bf16_t)tile[orr + j][oc + i];
    *(bf16x8*)&d[(size_t)(c0 + oc + i) * R + r0 + orr] = o;
  }
}

// ---------------- small prep: WtIn transpose + x cvt + fp64 gate-prep ------------
// z in [0,256) WtIn tiles, [256,4352) x cvt, [4352,4416) gate_prep.
__global__ void k_prep_small(const float* __restrict__ W_in, const float* __restrict__ x,
                             const float* __restrict__ Wgate, const float* __restrict__ b_in,
                             const float* __restrict__ b_gate,
                             bf16_t* __restrict__ WtIn, bf16_t* __restrict__ xbf,
                             double* __restrict__ G, double* __restrict__ cvec,
                             int* __restrict__ cnt) {
  const int z = blockIdx.x;
  if (z < 256) {
    __shared__ float tile[64][65];
    transpose_tile(W_in, WtIn, DIN, DH, z & 15, z >> 4, tile);
    return;
  }
  if (z < 4352) {
    const int i = (z - 256) * 256 + threadIdx.x;
    const float4 v = *(const float4*)(x + (size_t)i * 4);
    bf16x4 o;
    o.x = (bf16_t)v.x; o.y = (bf16_t)v.y; o.z = (bf16_t)v.z; o.w = (bf16_t)v.w;
    *(bf16x4*)(xbf + (size_t)i * 4) = o;
    return;
  }
  // gate_prep: 64 blocks x 4 waves = 256 waves over d in [0, DIN]
  const int b = z - 4352;
  if (b == 0 && threadIdx.x < 8) cnt[threadIdx.x] = 0;
  const int lane = threadIdx.x & 63;
  const int wave = b * 4 + (threadIdx.x >> 6);
  for (int d = wave; d <= DIN; d += 256) {
    const float* row = (d < DIN) ? (W_in + (size_t)d * DH) : b_in;
    double acc[8] = {0, 0, 0, 0, 0, 0, 0, 0};
    for (int k = lane; k < DH; k += 64) {
      const double xv = (double)row[k];
      const float* g = Wgate + (size_t)k * NEXP;
#pragma unroll
      for (int ee = 0; ee < 8; ++ee) acc[ee] += xv * (double)g[ee];
    }
#pragma unroll
    for (int ee = 0; ee < 8; ++ee) {
      double a = acc[ee];
      for (int o = 32; o > 0; o >>= 1) a += __shfl_down(a, o);
      acc[ee] = a;
    }
    if (lane == 0) {
      if (d < DIN) {
#pragma unroll
        for (int ee = 0; ee < 8; ++ee) G[(size_t)d * 8 + ee] = acc[ee];
      } else {
#pragma unroll
        for (int ee = 0; ee < 8; ++ee) cvec[ee] = acc[ee] + (double)b_gate[ee];
      }
    }
  }
}

// moe_bf16[t] = bf16(eout[t][0] + eout[t][1])
__global__ void k_combine(const bf16_t* __restrict__ eout, bf16_t* __restrict__ moebf) {
  const int i = blockIdx.x * blockDim.x + threadIdx.x;
  const int t = i >> 8;
  const int q = (i & 255) * 4;
  const bf16x4 a = *(const bf16x4*)(eout + ((size_t)t * 2) * DH + q);
  const bf16x4 b = *(const bf16x4*)(eout + ((size_t)t * 2 + 1) * DH + q);
  bf16x4 o;
  o.x = (bf16_t)((float)a.x + (float)b.x);
  o.y = (bf16_t)((float)a.y + (float)b.y);
  o.z = (bf16_t)((float)a.z + (float)b.z);
  o.w = (bf16_t)((float)a.w + (float)b.w);
  *(bf16x4*)(moebf + (size_t)t * DH + q) = o;
}

// ---------------- MEGA launch: GEMM0 ∥ gating ∥ W1/W2/Wout transposes ------------
// grid dim3(8,32,70): z==0 -> 128x128 GEMM0 tile; z in [1,5) -> gating (4 tok/blk);
// z in [5,70) -> transpose tiles: linear id [0,8192) W1, [8192,16384) W2,
// [16384,16640) Wout.  No intra-launch dependencies.
__global__ __launch_bounds__(256, 3) void k_mega(
    const bf16_t* __restrict__ A, const bf16_t* __restrict__ B,
    const float* __restrict__ bias, bf16_t* __restrict__ Cbase,
    const float* __restrict__ x, const double* __restrict__ G,
    const double* __restrict__ cvec, int* __restrict__ cnt,
    int* __restrict__ list, float* __restrict__ wlist,
    const float* __restrict__ W1, const float* __restrict__ W2,
    const float* __restrict__ W_out,
    bf16_t* __restrict__ Wt1, bf16_t* __restrict__ Wt2, bf16_t* __restrict__ WtOut) {
  constexpr int N = DH, K = DIN;

  __shared__ bf16_t As[3][128 * 32];
  __shared__ bf16_t Bs[3][128 * 32];

  if (blockIdx.z >= 5) {
    // ---- transpose backfill (reuse As as the f32 tile buffer: 24 KB > 16.6 KB) ----
    const int t6 = (blockIdx.z - 5) * 256 + blockIdx.y * 8 + blockIdx.x;
    if (t6 < 8192) {
      const int e = t6 >> 10, tt = t6 & 1023;
      transpose_tile(W1 + (size_t)e * DH * DMOE, Wt1 + (size_t)e * DH * DMOE,
                     DH, DMOE, tt & 63, tt >> 6, As);
    } else if (t6 < 16384) {
      const int l = t6 - 8192, e = l >> 10, tt = l & 1023;
      transpose_tile(W2 + (size_t)e * DMOE * DH, Wt2 + (size_t)e * DMOE * DH,
                     DMOE, DH, tt & 15, tt >> 4, As);
    } else {
      const int tt = t6 - 16384;
      transpose_tile(W_out, WtOut, DH, DH, tt & 15, tt >> 4, As);
    }
    return;
  }

  if (blockIdx.z > 0) {
    // ---- gating: 4 tokens per block, fp64 logits, softmax, top-2, scatter ----
    const int lane = threadIdx.x & 63;
    const int bl = (blockIdx.z - 1) * 256 + blockIdx.y * 8 + blockIdx.x;
    const int t = bl * 4 + (threadIdx.x >> 6);
    const float* xr = x + (size_t)t * DIN;
    double acc[8] = {0, 0, 0, 0, 0, 0, 0, 0};
    for (int d = lane; d < DIN; d += 64) {
      const double xv = (double)xr[d];
      const double* g = G + (size_t)d * 8;
#pragma unroll
      for (int ee = 0; ee < 8; ++ee) acc[ee] += xv * g[ee];
    }
#pragma unroll
    for (int ee = 0; ee < 8; ++ee) {
      double a = acc[ee];
      for (int o = 32; o > 0; o >>= 1) a += __shfl_down(a, o);
      acc[ee] = a;
    }
    if (lane == 0) {
      double l[8];
#pragma unroll
      for (int ee = 0; ee < 8; ++ee) l[ee] = acc[ee] + cvec[ee];
      double m = l[0];
#pragma unroll
      for (int ee = 1; ee < 8; ++ee) m = fmax(m, l[ee]);
      double p[8];
#pragma unroll
      for (int ee = 0; ee < 8; ++ee) p[ee] = exp(l[ee] - m);
      int i1 = 0;
#pragma unroll
      for (int ee = 1; ee < 8; ++ee)
        if (p[ee] > p[i1]) i1 = ee;
      int i2 = (i1 == 0) ? 1 : 0;
#pragma unroll
      for (int ee = 0; ee < 8; ++ee)
        if (ee != i1 && p[ee] > p[i2]) i2 = ee;
      const double s2 = p[i1] + p[i2];
      const float w1 = (float)(p[i1] / s2);
      const float w2 = (float)(p[i2] / s2);
      int lp = atomicAdd(&cnt[i1], 1);
      list[i1 * NTOK + lp] = t * 2;
      wlist[i1 * NTOK + lp] = w1;
      lp = atomicAdd(&cnt[i2], 1);
      list[i2 * NTOK + lp] = t * 2 + 1;
      wlist[i2 * NTOK + lp] = w2;
    }
    return;
  }

  // ---- GEMM0: 128x128 BK=32, 4 waves, 3-buf depth-2 counted vmcnt, swizzled ----
  const int mblk = blockIdx.y, nblk = blockIdx.x;

  const int tid = threadIdx.x;
  const int lane = tid & 63;
  const int wid = tid >> 6;
  const int wr = wid >> 1, wc = wid & 1;

  const int srow0 = wid * 32 + (lane >> 2);
  const int srow1 = srow0 + 16;
  const int skcol = ((lane & 3) ^ ((lane >> 3) & 3)) * 8;

  const bf16_t* aptr0 = A + (size_t)(mblk * 128 + srow0) * K + skcol;
  const bf16_t* aptr1 = A + (size_t)(mblk * 128 + srow1) * K + skcol;
  const bf16_t* bptr0 = B + (size_t)(nblk * 128 + srow0) * K + skcol;
  const bf16_t* bptr1 = B + (size_t)(nblk * 128 + srow1) * K + skcol;

  const int ldsOfsA0 = (wid * 32) * 32;
  const int ldsOfsA1 = (wid * 32 + 16) * 32;

  f32x4 acc[4][4] = {};
  const int nkt = K >> 5;

  auto stage = [&](int buf, int kt) {
    const size_t ko = (size_t)kt * 32;
    gload_lds16(aptr0 + ko, &As[buf][ldsOfsA0]);
    gload_lds16(aptr1 + ko, &As[buf][ldsOfsA1]);
    gload_lds16(bptr0 + ko, &Bs[buf][ldsOfsA0]);
    gload_lds16(bptr1 + ko, &Bs[buf][ldsOfsA1]);
  };

  stage(0, 0);
  if (nkt > 1) stage(1, 1);

  const int fr = lane & 15;
  const int s0 = (((lane >> 4) ^ ((fr >> 1) & 3)) << 3);

  int cur = 0;
  for (int kt = 0; kt < nkt; ++kt) {
    int nxt = cur + 2;
    if (nxt >= 3) nxt -= 3;
    if (kt + 2 < nkt) {
      stage(nxt, kt + 2);
      asm volatile("s_waitcnt vmcnt(8)" ::: "memory");
    } else if (kt + 1 < nkt) {
      asm volatile("s_waitcnt vmcnt(4)" ::: "memory");
    } else {
      asm volatile("s_waitcnt vmcnt(0)" ::: "memory");
    }
    __builtin_amdgcn_s_barrier();

    bf16x8 af[4], bfr[4];
#pragma unroll
    for (int m = 0; m < 4; ++m)
      af[m] = *(const bf16x8*)&As[cur][(wr * 64 + m * 16 + fr) * 32 + s0];
#pragma unroll
    for (int n = 0; n < 4; ++n)
      bfr[n] = *(const bf16x8*)&Bs[cur][(wc * 64 + n * 16 + fr) * 32 + s0];
#pragma unroll
    for (int m = 0; m < 4; ++m)
#pragma unroll
      for (int n = 0; n < 4; ++n)
        acc[m][n] = __builtin_amdgcn_mfma_f32_16x16x32_bf16(af[m], bfr[n], acc[m][n], 0, 0, 0);

    __builtin_amdgcn_s_barrier();
    cur += 1;
    if (cur >= 3) cur -= 3;
  }

  const int colBase = nblk * 128 + wc * 64 + (lane & 15);
  const int rowBase = mblk * 128 + wr * 64 + ((lane >> 4) << 2);
#pragma unroll
  for (int n = 0; n < 4; ++n) {
    const int c = colBase + n * 16;
    const float bv = bias[c];
#pragma unroll
    for (int m = 0; m < 4; ++m) {
#pragma unroll
      for (int j = 0; j < 4; ++j) {
        const int r = rowBase + m * 16 + j;
        Cbase[(size_t)r * N + c] = (bf16_t)(acc[m][n][j] + bv);
      }
    }
  }
}

// ---------------- 128x128 BK=32 plain GEMM, 4 waves (GEMM3, fp32 out) ----------
__global__ __launch_bounds__(256, 3) void k_gemm_out(
    const bf16_t* __restrict__ A, const bf16_t* __restrict__ B,
    const float* __restrict__ bias, float* __restrict__ Cbase,
    int M, int N, int K) {
  const int mblk = blockIdx.y, nblk = blockIdx.x;

  __shared__ bf16_t As[3][128 * 32];
  __shared__ bf16_t Bs[3][128 * 32];

  const int tid = threadIdx.x;
  const int lane = tid & 63;
  const int wid = tid >> 6;
  const int wr = wid >> 1, wc = wid & 1;

  const int srow0 = wid * 32 + (lane >> 2);
  const int srow1 = srow0 + 16;
  const int skcol = ((lane & 3) ^ ((lane >> 3) & 3)) * 8;

  const bf16_t* aptr0 = A + (size_t)(mblk * 128 + srow0) * K + skcol;
  const bf16_t* aptr1 = A + (size_t)(mblk * 128 + srow1) * K + skcol;
  const bf16_t* bptr0 = B + (size_t)(nblk * 128 + srow0) * K + skcol;
  const bf16_t* bptr1 = B + (size_t)(nblk * 128 + srow1) * K + skcol;

  const int ldsOfsA0 = (wid * 32) * 32;
  const int ldsOfsA1 = (wid * 32 + 16) * 32;

  f32x4 acc[4][4] = {};
  const int nkt = K >> 5;

  auto stage = [&](int buf, int kt) {
    const size_t ko = (size_t)kt * 32;
    gload_lds16(aptr0 + ko, &As[buf][ldsOfsA0]);
    gload_lds16(aptr1 + ko, &As[buf][ldsOfsA1]);
    gload_lds16(bptr0 + ko, &Bs[buf][ldsOfsA0]);
    gload_lds16(bptr1 + ko, &Bs[buf][ldsOfsA1]);
  };

  stage(0, 0);
  if (nkt > 1) stage(1, 1);

  const int fr = lane & 15;
  const int s0 = (((lane >> 4) ^ ((fr >> 1) & 3)) << 3);

  int cur = 0;
  for (int kt = 0; kt < nkt; ++kt) {
    int nxt = cur + 2;
    if (nxt >= 3) nxt -= 3;
    if (kt + 2 < nkt) {
      stage(nxt, kt + 2);
      asm volatile("s_waitcnt vmcnt(8)" ::: "memory");
    } else if (kt + 1 < nkt) {
      asm volatile("s_waitcnt vmcnt(4)" ::: "memory");
    } else {
      asm volatile("s_waitcnt vmcnt(0)" ::: "memory");
    }
    __builtin_amdgcn_s_barrier();

    bf16x8 af[4], bfr[4];
#pragma unroll
    for (int m = 0; m < 4; ++m)
      af[m] = *(const bf16x8*)&As[cur][(wr * 64 + m * 16 + fr) * 32 + s0];
#pragma unroll
    for (int n = 0; n < 4; ++n)
      bfr[n] = *(const bf16x8*)&Bs[cur][(wc * 64 + n * 16 + fr) * 32 + s0];
#pragma unroll
    for (int m = 0; m < 4; ++m)
#pragma unroll
      for (int n = 0; n < 4; ++n)
        acc[m][n] = __builtin_amdgcn_mfma_f32_16x16x32_bf16(af[m], bfr[n], acc[m][n], 0, 0, 0);

    __builtin_amdgcn_s_barrier();
    cur += 1;
    if (cur >= 3) cur -= 3;
  }

  const int colBase = nblk * 128 + wc * 64 + (lane & 15);
  const int rowBase = mblk * 128 + wr * 64 + ((lane >> 4) << 2);
#pragma unroll
  for (int n = 0; n < 4; ++n) {
    const int c = colBase + n * 16;
    const float bv = bias[c];
#pragma unroll
    for (int m = 0; m < 4; ++m) {
#pragma unroll
      for (int j = 0; j < 4; ++j) {
        const int r = rowBase + m * 16 + j;
        Cbase[(size_t)r * N + c] = acc[m][n][j] + bv;
      }
    }
  }
}

// ---------------- 256x128 BK=32 expert GEMM1, 8 waves (R15-proven) ------
__global__ __launch_bounds__(512, 4) void k_gemm1(
    const bf16_t* __restrict__ Abase, const bf16_t* __restrict__ Bbase,
    const float* __restrict__ biasBase, bf16_t* __restrict__ Cbase,
    int N, int K,
    const int* __restrict__ cnt, const int* __restrict__ listBase) {
  const int e = blockIdx.z;
  const int mblk = blockIdx.y, nblk = blockIdx.x;
  const int Mloc = cnt[e];
  if (mblk * 256 >= Mloc) return;
  int rowOff = 0;
  for (int i = 0; i < NEXP; ++i) rowOff += (i < e) ? cnt[i] : 0;
  const bf16_t* B = Bbase + (size_t)e * N * K;
  const float* bias = biasBase + (size_t)e * N;
  const int* myList = listBase + e * NTOK;

  __shared__ bf16_t As[3][256 * 32];
  __shared__ bf16_t Bs[3][128 * 32];

  const int tid = threadIdx.x;
  const int lane = tid & 63;
  const int wid = tid >> 6;
  const int wr = wid >> 1, wc = wid & 1;

  const int subr = lane >> 2;
  const int skcol = ((lane & 3) ^ ((lane >> 3) & 3)) * 8;

  uint32_t aofs[2];
#pragma unroll
  for (int l = 0; l < 2; ++l) {
    int ar = mblk * 256 + (wid * 2 + l) * 16 + subr;
    if (ar > Mloc - 1) ar = Mloc - 1;
    aofs[l] = (uint32_t)(myList[ar] >> 1) * (uint32_t)K + skcol;
  }
  const uint32_t bofs = (uint32_t)(nblk * 128 + wid * 16 + subr) * (uint32_t)K + skcol;

  f32x4 acc[4][4] = {};
  const int nkt = K >> 5;

  auto stage = [&](int buf, int kt) {
    const uint32_t ko = (uint32_t)kt * 32;
    gload_lds16(Abase + aofs[0] + ko, &As[buf][(wid * 2 + 0) * 512]);
    gload_lds16(Abase + aofs[1] + ko, &As[buf][(wid * 2 + 1) * 512]);
    gload_lds16(B + bofs + ko, &Bs[buf][wid * 512]);
  };

  stage(0, 0);
  if (nkt > 1) stage(1, 1);

  const int fr = lane & 15;
  const int s0 = (((lane >> 4) ^ ((fr >> 1) & 3)) << 3);

  int cur = 0;
  for (int kt = 0; kt < nkt; ++kt) {
    int nxt = cur + 2;
    if (nxt >= 3) nxt -= 3;
    if (kt + 2 < nkt) {
      stage(nxt, kt + 2);
      asm volatile("s_waitcnt vmcnt(6)" ::: "memory");
    } else if (kt + 1 < nkt) {
      asm volatile("s_waitcnt vmcnt(3)" ::: "memory");
    } else {
      asm volatile("s_waitcnt vmcnt(0)" ::: "memory");
    }
    __builtin_amdgcn_s_barrier();

    bf16x8 af[4], bfr[4];
#pragma unroll
    for (int m = 0; m < 4; ++m)
      af[m] = *(const bf16x8*)&As[cur][(wr * 64 + m * 16 + fr) * 32 + s0];
#pragma unroll
    for (int n = 0; n < 4; ++n)
      bfr[n] = *(const bf16x8*)&Bs[cur][(wc * 64 + n * 16 + fr) * 32 + s0];
#pragma unroll
    for (int m = 0; m < 4; ++m)
#pragma unroll
      for (int n = 0; n < 4; ++n)
        acc[m][n] = __builtin_amdgcn_mfma_f32_16x16x32_bf16(af[m], bfr[n], acc[m][n], 0, 0, 0);

    __builtin_amdgcn_s_barrier();
    cur += 1;
    if (cur >= 3) cur -= 3;
  }

  const int colBase = nblk * 128 + wc * 64 + (lane & 15);
  const int rowBase = mblk * 256 + wr * 64 + ((lane >> 4) << 2);
#pragma unroll
  for (int n = 0; n < 4; ++n) {
    const int c = colBase + n * 16;
    const float bv = bias[c];
#pragma unroll
    for (int m = 0; m < 4; ++m) {
#pragma unroll
      for (int j = 0; j < 4; ++j) {
        const int r = rowBase + m * 16 + j;
        if (r < Mloc) {
          Cbase[(size_t)(rowOff + r) * N + c] = (bf16_t)fmaxf(acc[m][n][j] + bv, 0.0f);
        }
      }
    }
  }
}

// ---------------- 128x128 BK=32 expert GEMM2, 4 waves (R15-proven, best of 4) ----
__global__ __launch_bounds__(256, 3) void k_gemm_e2(
    const bf16_t* __restrict__ Abase, const bf16_t* __restrict__ Bbase,
    const float* __restrict__ biasBase, bf16_t* __restrict__ Cbase,
    int N, int K,
    const int* __restrict__ cnt, const int* __restrict__ listBase,
    const float* __restrict__ wlistBase) {
  const int e = blockIdx.z;
  const int mblk = blockIdx.y, nblk = blockIdx.x;
  const int Mloc = cnt[e];
  if (mblk * 128 >= Mloc) return;
  int rowOff = 0;
  for (int i = 0; i < NEXP; ++i) rowOff += (i < e) ? cnt[i] : 0;
  const bf16_t* B = Bbase + (size_t)e * N * K;
  const float* bias = biasBase + (size_t)e * N;
  const int* myList = listBase + e * NTOK;
  const float* myW = wlistBase + e * NTOK;
  const bf16_t* A = Abase + (size_t)rowOff * K;

  __shared__ bf16_t As[3][128 * 32];
  __shared__ bf16_t Bs[3][128 * 32];

  const int tid = threadIdx.x;
  const int lane = tid & 63;
  const int wid = tid >> 6;
  const int wr = wid >> 1, wc = wid & 1;

  const int srow0 = wid * 32 + (lane >> 2);
  const int srow1 = srow0 + 16;
  const int skcol = ((lane & 3) ^ ((lane >> 3) & 3)) * 8;

  int ar0 = mblk * 128 + srow0;
  int ar1 = mblk * 128 + srow1;
  if (ar0 > Mloc - 1) ar0 = Mloc - 1;
  if (ar1 > Mloc - 1) ar1 = Mloc - 1;
  const bf16_t* aptr0 = A + (size_t)ar0 * K + skcol;
  const bf16_t* aptr1 = A + (size_t)ar1 * K + skcol;
  const bf16_t* bptr0 = B + (size_t)(nblk * 128 + srow0) * K + skcol;
  const bf16_t* bptr1 = B + (size_t)(nblk * 128 + srow1) * K + skcol;

  const int ldsOfsA0 = (wid * 32) * 32;
  const int ldsOfsA1 = (wid * 32 + 16) * 32;

  f32x4 acc[4][4] = {};
  const int nkt = K >> 5;

  auto stage = [&](int buf, int kt) {
    const size_t ko = (size_t)kt * 32;
    gload_lds16(aptr0 + ko, &As[buf][ldsOfsA0]);
    gload_lds16(aptr1 + ko, &As[buf][ldsOfsA1]);
    gload_lds16(bptr0 + ko, &Bs[buf][ldsOfsA0]);
    gload_lds16(bptr1 + ko, &Bs[buf][ldsOfsA1]);
  };

  stage(0, 0);
  if (nkt > 1) stage(1, 1);

  const int fr = lane & 15;
  const int s0 = (((lane >> 4) ^ ((fr >> 1) & 3)) << 3);

  int cur = 0;
  for (int kt = 0; kt < nkt; ++kt) {
    int nxt = cur + 2;
    if (nxt >= 3) nxt -= 3;
    if (kt + 2 < nkt) {
      stage(nxt, kt + 2);
      asm volatile("s_waitcnt vmcnt(8)" ::: "memory");
    } else if (kt + 1 < nkt) {
      asm volatile("s_waitcnt vmcnt(4)" ::: "memory");
    } else {
      asm volatile("s_waitcnt vmcnt(0)" ::: "memory");
    }
    __builtin_amdgcn_s_barrier();

    bf16x8 af[4], bfr[4];
#pragma unroll
    for (int m = 0; m < 4; ++m)
      af[m] = *(const bf16x8*)&As[cur][(wr * 64 + m * 16 + fr) * 32 + s0];
#pragma unroll
    for (int n = 0; n < 4; ++n)
      bfr[n] = *(const bf16x8*)&Bs[cur][(wc * 64 + n * 16 + fr) * 32 + s0];
#pragma unroll
    for (int m = 0; m < 4; ++m)
#pragma unroll
      for (int n = 0; n < 4; ++n)
        acc[m][n] = __builtin_amdgcn_mfma_f32_16x16x32_bf16(af[m], bfr[n], acc[m][n], 0, 0, 0);

    __builtin_amdgcn_s_barrier();
    cur += 1;
    if (cur >= 3) cur -= 3;
  }

  const int colBase = nblk * 128 + wc * 64 + (lane & 15);
  const int rowBase = mblk * 128 + wr * 64 + ((lane >> 4) << 2);
#pragma unroll
  for (int n = 0; n < 4; ++n) {
    const int c = colBase + n * 16;
    const float bv = bias[c];
#pragma unroll
    for (int m = 0; m < 4; ++m) {
#pragma unroll
      for (int j = 0; j < 4; ++j) {
        const int r = rowBase + m * 16 + j;
        if (r < Mloc) {
          const int entry = myList[r];
          const float w = myW[r];
          Cbase[(size_t)entry * DH + c] = (bf16_t)((acc[m][n][j] + bv) * w);
        }
      }
    }
  }
}

// ---------------- launch ----------------

extern "C" void kernel_launch(void* const* d_in, const int* in_sizes, int n_in,
                              void* d_out, int out_size, void* d_ws, size_t ws_size,
                              hipStream_t stream) {
  const float* x      = (const float*)d_in[0];
  const float* W_in   = (const float*)d_in[1];
  const float* b_in   = (const float*)d_in[2];
  const float* W_gate = (const float*)d_in[3];
  const float* b_gate = (const float*)d_in[4];
  const float* W1     = (const float*)d_in[5];
  const float* b1     = (const float*)d_in[6];
  const float* W2     = (const float*)d_in[7];
  const float* b2     = (const float*)d_in[8];
  const float* W_out  = (const float*)d_in[9];
  const float* b_out  = (const float*)d_in[10];

  char* ws = (char*)d_ws;
  size_t off = 0;
  auto alloc = [&](size_t bytes) -> void* {
    void* p = ws + off;
    off += (bytes + 255) & ~(size_t)255;
    return p;
  };

  bf16_t* WtIn  = (bf16_t*)alloc((size_t)DH * DIN * 2);
  bf16_t* Wt1   = (bf16_t*)alloc((size_t)NEXP * DMOE * DH * 2);
  bf16_t* Wt2   = (bf16_t*)alloc((size_t)NEXP * DH * DMOE * 2);
  bf16_t* WtOut = (bf16_t*)alloc((size_t)DH * DH * 2);
  bf16_t* xbf   = (bf16_t*)alloc((size_t)NTOK * DIN * 2);
  bf16_t* hbf   = (bf16_t*)alloc((size_t)NTOK * DH * 2);
  bf16_t* mid   = (bf16_t*)alloc((size_t)2 * NTOK * DMOE * 2);
  bf16_t* eoutb = (bf16_t*)alloc((size_t)2 * NTOK * DH * 2);
  bf16_t* moebf = (bf16_t*)alloc((size_t)NTOK * DH * 2);
  double* G     = (double*)alloc((size_t)DIN * 8 * 8);
  double* cvec  = (double*)alloc(8 * 8);
  int*    cnt   = (int*)alloc(NEXP * 4);
  int*    list  = (int*)alloc((size_t)NEXP * NTOK * 4);
  float*  wlist = (float*)alloc((size_t)NEXP * NTOK * 4);

  // small prep: WtIn transpose + x cvt + fp64 gate-prep (cnt zeroed)
  k_prep_small<<<4416, 256, 0, stream>>>(W_in, x, W_gate, b_in, b_gate,
                                         WtIn, xbf, G, cvec, cnt);

  // MEGA: GEMM0 (z=0) ∥ gating (z=1..4) ∥ W1/W2/Wout transposes (z=5..69)
  k_mega<<<dim3(DH / 128, NTOK / 128, 70), 256, 0, stream>>>(
      xbf, WtIn, b_in, hbf, x, G, cvec, cnt, list, wlist,
      W1, W2, W_out, Wt1, Wt2, WtOut);

  // mid = relu(h_gathered @ W1[e] + b1[e])  (256x128, 8 waves)
  k_gemm1<<<dim3(DMOE / 128, NTOK / 256, NEXP), 512, 0, stream>>>(
      hbf, Wt1, b1, mid, DMOE, DH, cnt, list);
  // eout[entry] = bf16((mid @ W2[e] + b2[e]) * route_w)  (128^2, best-measured)
  k_gemm_e2<<<dim3(DH / 128, NTOK / 128, NEXP), 256, 0, stream>>>(
      mid, Wt2, b2, eoutb, DH, DMOE, cnt, list, wlist);
  k_combine<<<NTOK * DH / 4 / 256, 256, 0, stream>>>(eoutb, moebf);
  // out = moe @ W_out + b_out (fp32 out)
  k_gemm_out<<<dim3(DH / 128, NTOK / 128, 1), 256, 0, stream>>>(
      moebf, WtOut, b_out, (float*)d_out, NTOK, DH, DH);
}

// Round 22
// 490.028 us; speedup vs baseline: 1.1890x; 1.0499x over previous
//
#include <hip/hip_runtime.h>
#include <hip/hip_bf16.h>

typedef __bf16 bf16_t;
typedef bf16_t bf16x8 __attribute__((ext_vector_type(8)));
typedef bf16_t bf16x4 __attribute__((ext_vector_type(4)));
typedef float f32x4 __attribute__((ext_vector_type(4)));

#define DIN 1024
#define DH 1024
#define DMOE 4096
#define NEXP 8
#define NTOK 4096

__device__ __forceinline__ void gload_lds16(const bf16_t* g, bf16_t* l) {
  __builtin_amdgcn_global_load_lds(
      (const __attribute__((address_space(1))) void*)g,
      (__attribute__((address_space(3))) void*)l, 16, 0, 0);
}

// 64x64 transpose+cvt tile body, 256 threads (R14-proven). smem >= 64*65*4 B.
__device__ __forceinline__ void transpose_tile(const float* __restrict__ s,
                                               bf16_t* __restrict__ d, int R, int C,
                                               int tx, int ty, void* smem) {
  float (*tile)[65] = (float(*)[65])smem;
  const int c0 = tx * 64, r0 = ty * 64;
  const int t = threadIdx.x;
  const int rr = t >> 4;
  const int cc = (t & 15) << 2;
#pragma unroll
  for (int i = 0; i < 64; i += 16) {
    const float4 v = *(const float4*)&s[(size_t)(r0 + rr + i) * C + c0 + cc];
    tile[rr + i][cc + 0] = v.x;
    tile[rr + i][cc + 1] = v.y;
    tile[rr + i][cc + 2] = v.z;
    tile[rr + i][cc + 3] = v.w;
  }
  __syncthreads();
  const int orr = (t & 7) * 8;
  const int oc = t >> 3;
#pragma unroll
  for (int i = 0; i < 64; i += 32) {
    bf16x8 o;
#pragma unroll
    for (int j = 0; j < 8; ++j) o[j] = (bf16_t)tile[orr + j][oc + i];
    *(bf16x8*)&d[(size_t)(c0 + oc + i) * R + r0 + orr] = o;
  }
}

// 64x64 transpose+cvt tile body, 512 threads.  Store bank = (8a+b+j) mod 32 over
// a,b in [0,8) -> exact 2-way (free).
__device__ __forceinline__ void transpose_tile512(const float* __restrict__ s,
                                                  bf16_t* __restrict__ d, int R, int C,
                                                  int tx, int ty, void* smem) {
  float (*tile)[65] = (float(*)[65])smem;
  const int c0 = tx * 64, r0 = ty * 64;
  const int t = threadIdx.x;      // 0..511
  const int rr = t >> 4;          // 0..31
  const int cc = (t & 15) << 2;
#pragma unroll
  for (int i = 0; i < 64; i += 32) {
    const float4 v = *(const float4*)&s[(size_t)(r0 + rr + i) * C + c0 + cc];
    tile[rr + i][cc + 0] = v.x;
    tile[rr + i][cc + 1] = v.y;
    tile[rr + i][cc + 2] = v.z;
    tile[rr + i][cc + 3] = v.w;
  }
  __syncthreads();
  const int orr = (t & 7) * 8;
  const int oc = t >> 3;          // 0..63
  bf16x8 o;
#pragma unroll
  for (int j = 0; j < 8; ++j) o[j] = (bf16_t)tile[orr + j][oc];
  *(bf16x8*)&d[(size_t)(c0 + oc) * R + r0 + orr] = o;
}

// ---------------- small prep: WtIn transpose + x cvt + fp64 gate-prep ------------
__global__ void k_prep_small(const float* __restrict__ W_in, const float* __restrict__ x,
                             const float* __restrict__ Wgate, const float* __restrict__ b_in,
                             const float* __restrict__ b_gate,
                             bf16_t* __restrict__ WtIn, bf16_t* __restrict__ xbf,
                             double* __restrict__ G, double* __restrict__ cvec,
                             int* __restrict__ cnt) {
  const int z = blockIdx.x;
  if (z < 256) {
    __shared__ float tile[64][65];
    transpose_tile(W_in, WtIn, DIN, DH, z & 15, z >> 4, tile);
    return;
  }
  if (z < 4352) {
    const int i = (z - 256) * 256 + threadIdx.x;
    const float4 v = *(const float4*)(x + (size_t)i * 4);
    bf16x4 o;
    o.x = (bf16_t)v.x; o.y = (bf16_t)v.y; o.z = (bf16_t)v.z; o.w = (bf16_t)v.w;
    *(bf16x4*)(xbf + (size_t)i * 4) = o;
    return;
  }
  const int b = z - 4352;
  if (b == 0 && threadIdx.x < 8) cnt[threadIdx.x] = 0;
  const int lane = threadIdx.x & 63;
  const int wave = b * 4 + (threadIdx.x >> 6);
  for (int d = wave; d <= DIN; d += 256) {
    const float* row = (d < DIN) ? (W_in + (size_t)d * DH) : b_in;
    double acc[8] = {0, 0, 0, 0, 0, 0, 0, 0};
    for (int k = lane; k < DH; k += 64) {
      const double xv = (double)row[k];
      const float* g = Wgate + (size_t)k * NEXP;
#pragma unroll
      for (int ee = 0; ee < 8; ++ee) acc[ee] += xv * (double)g[ee];
    }
#pragma unroll
    for (int ee = 0; ee < 8; ++ee) {
      double a = acc[ee];
      for (int o = 32; o > 0; o >>= 1) a += __shfl_down(a, o);
      acc[ee] = a;
    }
    if (lane == 0) {
      if (d < DIN) {
#pragma unroll
        for (int ee = 0; ee < 8; ++ee) G[(size_t)d * 8 + ee] = acc[ee];
      } else {
#pragma unroll
        for (int ee = 0; ee < 8; ++ee) cvec[ee] = acc[ee] + (double)b_gate[ee];
      }
    }
  }
}

// moe_bf16[t] = bf16(eout[t][0] + eout[t][1])
__global__ void k_combine(const bf16_t* __restrict__ eout, bf16_t* __restrict__ moebf) {
  const int i = blockIdx.x * blockDim.x + threadIdx.x;
  const int t = i >> 8;
  const int q = (i & 255) * 4;
  const bf16x4 a = *(const bf16x4*)(eout + ((size_t)t * 2) * DH + q);
  const bf16x4 b = *(const bf16x4*)(eout + ((size_t)t * 2 + 1) * DH + q);
  bf16x4 o;
  o.x = (bf16_t)((float)a.x + (float)b.x);
  o.y = (bf16_t)((float)a.y + (float)b.y);
  o.z = (bf16_t)((float)a.z + (float)b.z);
  o.w = (bf16_t)((float)a.w + (float)b.w);
  *(bf16x4*)(moebf + (size_t)t * DH + q) = o;
}

// ---------------- MEGA launch: GEMM0 ∥ gating ∥ W1 transpose --------------------
// grid dim3(8,32,37): z==0 GEMM0; z in [1,5) gating; z in [5,37) W1 tiles.
__global__ __launch_bounds__(256, 3) void k_mega(
    const bf16_t* __restrict__ A, const bf16_t* __restrict__ B,
    const float* __restrict__ bias, bf16_t* __restrict__ Cbase,
    const float* __restrict__ x, const double* __restrict__ G,
    const double* __restrict__ cvec, int* __restrict__ cnt,
    int* __restrict__ list, float* __restrict__ wlist,
    const float* __restrict__ W1, bf16_t* __restrict__ Wt1) {
  constexpr int N = DH, K = DIN;

  __shared__ bf16_t As[3][128 * 32];
  __shared__ bf16_t Bs[3][128 * 32];

  if (blockIdx.z >= 5) {
    const int t6 = (blockIdx.z - 5) * 256 + blockIdx.y * 8 + blockIdx.x;
    const int e = t6 >> 10, tt = t6 & 1023;
    transpose_tile(W1 + (size_t)e * DH * DMOE, Wt1 + (size_t)e * DH * DMOE,
                   DH, DMOE, tt & 63, tt >> 6, As);
    return;
  }

  if (blockIdx.z > 0) {
    const int lane = threadIdx.x & 63;
    const int bl = (blockIdx.z - 1) * 256 + blockIdx.y * 8 + blockIdx.x;
    const int t = bl * 4 + (threadIdx.x >> 6);
    const float* xr = x + (size_t)t * DIN;
    double acc[8] = {0, 0, 0, 0, 0, 0, 0, 0};
    for (int d = lane; d < DIN; d += 64) {
      const double xv = (double)xr[d];
      const double* g = G + (size_t)d * 8;
#pragma unroll
      for (int ee = 0; ee < 8; ++ee) acc[ee] += xv * g[ee];
    }
#pragma unroll
    for (int ee = 0; ee < 8; ++ee) {
      double a = acc[ee];
      for (int o = 32; o > 0; o >>= 1) a += __shfl_down(a, o);
      acc[ee] = a;
    }
    if (lane == 0) {
      double l[8];
#pragma unroll
      for (int ee = 0; ee < 8; ++ee) l[ee] = acc[ee] + cvec[ee];
      double m = l[0];
#pragma unroll
      for (int ee = 1; ee < 8; ++ee) m = fmax(m, l[ee]);
      double p[8];
#pragma unroll
      for (int ee = 0; ee < 8; ++ee) p[ee] = exp(l[ee] - m);
      int i1 = 0;
#pragma unroll
      for (int ee = 1; ee < 8; ++ee)
        if (p[ee] > p[i1]) i1 = ee;
      int i2 = (i1 == 0) ? 1 : 0;
#pragma unroll
      for (int ee = 0; ee < 8; ++ee)
        if (ee != i1 && p[ee] > p[i2]) i2 = ee;
      const double s2 = p[i1] + p[i2];
      const float w1 = (float)(p[i1] / s2);
      const float w2 = (float)(p[i2] / s2);
      int lp = atomicAdd(&cnt[i1], 1);
      list[i1 * NTOK + lp] = t * 2;
      wlist[i1 * NTOK + lp] = w1;
      lp = atomicAdd(&cnt[i2], 1);
      list[i2 * NTOK + lp] = t * 2 + 1;
      wlist[i2 * NTOK + lp] = w2;
    }
    return;
  }

  // ---- GEMM0: 128x128 BK=32, 4 waves, 3-buf depth-2 counted vmcnt, swizzled ----
  const int mblk = blockIdx.y, nblk = blockIdx.x;

  const int tid = threadIdx.x;
  const int lane = tid & 63;
  const int wid = tid >> 6;
  const int wr = wid >> 1, wc = wid & 1;

  const int srow0 = wid * 32 + (lane >> 2);
  const int srow1 = srow0 + 16;
  const int skcol = ((lane & 3) ^ ((lane >> 3) & 3)) * 8;

  const bf16_t* aptr0 = A + (size_t)(mblk * 128 + srow0) * K + skcol;
  const bf16_t* aptr1 = A + (size_t)(mblk * 128 + srow1) * K + skcol;
  const bf16_t* bptr0 = B + (size_t)(nblk * 128 + srow0) * K + skcol;
  const bf16_t* bptr1 = B + (size_t)(nblk * 128 + srow1) * K + skcol;

  const int ldsOfsA0 = (wid * 32) * 32;
  const int ldsOfsA1 = (wid * 32 + 16) * 32;

  f32x4 acc[4][4] = {};
  const int nkt = K >> 5;

  auto stage = [&](int buf, int kt) {
    const size_t ko = (size_t)kt * 32;
    gload_lds16(aptr0 + ko, &As[buf][ldsOfsA0]);
    gload_lds16(aptr1 + ko, &As[buf][ldsOfsA1]);
    gload_lds16(bptr0 + ko, &Bs[buf][ldsOfsA0]);
    gload_lds16(bptr1 + ko, &Bs[buf][ldsOfsA1]);
  };

  stage(0, 0);
  if (nkt > 1) stage(1, 1);

  const int fr = lane & 15;
  const int s0 = (((lane >> 4) ^ ((fr >> 1) & 3)) << 3);

  int cur = 0;
  for (int kt = 0; kt < nkt; ++kt) {
    int nxt = cur + 2;
    if (nxt >= 3) nxt -= 3;
    if (kt + 2 < nkt) {
      stage(nxt, kt + 2);
      asm volatile("s_waitcnt vmcnt(8)" ::: "memory");
    } else if (kt + 1 < nkt) {
      asm volatile("s_waitcnt vmcnt(4)" ::: "memory");
    } else {
      asm volatile("s_waitcnt vmcnt(0)" ::: "memory");
    }
    __builtin_amdgcn_s_barrier();

    bf16x8 af[4], bfr[4];
#pragma unroll
    for (int m = 0; m < 4; ++m)
      af[m] = *(const bf16x8*)&As[cur][(wr * 64 + m * 16 + fr) * 32 + s0];
#pragma unroll
    for (int n = 0; n < 4; ++n)
      bfr[n] = *(const bf16x8*)&Bs[cur][(wc * 64 + n * 16 + fr) * 32 + s0];
#pragma unroll
    for (int m = 0; m < 4; ++m)
#pragma unroll
      for (int n = 0; n < 4; ++n)
        acc[m][n] = __builtin_amdgcn_mfma_f32_16x16x32_bf16(af[m], bfr[n], acc[m][n], 0, 0, 0);

    __builtin_amdgcn_s_barrier();
    cur += 1;
    if (cur >= 3) cur -= 3;
  }

  const int colBase = nblk * 128 + wc * 64 + (lane & 15);
  const int rowBase = mblk * 128 + wr * 64 + ((lane >> 4) << 2);
#pragma unroll
  for (int n = 0; n < 4; ++n) {
    const int c = colBase + n * 16;
    const float bv = bias[c];
#pragma unroll
    for (int m = 0; m < 4; ++m) {
#pragma unroll
      for (int j = 0; j < 4; ++j) {
        const int r = rowBase + m * 16 + j;
        Cbase[(size_t)r * N + c] = (bf16_t)(acc[m][n][j] + bv);
      }
    }
  }
}

// ---------------- 128x128 BK=32 plain GEMM, 4 waves (GEMM3, fp32 out) ----------
__global__ __launch_bounds__(256, 3) void k_gemm_out(
    const bf16_t* __restrict__ A, const bf16_t* __restrict__ B,
    const float* __restrict__ bias, float* __restrict__ Cbase,
    int M, int N, int K) {
  const int mblk = blockIdx.y, nblk = blockIdx.x;

  __shared__ bf16_t As[3][128 * 32];
  __shared__ bf16_t Bs[3][128 * 32];

  const int tid = threadIdx.x;
  const int lane = tid & 63;
  const int wid = tid >> 6;
  const int wr = wid >> 1, wc = wid & 1;

  const int srow0 = wid * 32 + (lane >> 2);
  const int srow1 = srow0 + 16;
  const int skcol = ((lane & 3) ^ ((lane >> 3) & 3)) * 8;

  const bf16_t* aptr0 = A + (size_t)(mblk * 128 + srow0) * K + skcol;
  const bf16_t* aptr1 = A + (size_t)(mblk * 128 + srow1) * K + skcol;
  const bf16_t* bptr0 = B + (size_t)(nblk * 128 + srow0) * K + skcol;
  const bf16_t* bptr1 = B + (size_t)(nblk * 128 + srow1) * K + skcol;

  const int ldsOfsA0 = (wid * 32) * 32;
  const int ldsOfsA1 = (wid * 32 + 16) * 32;

  f32x4 acc[4][4] = {};
  const int nkt = K >> 5;

  auto stage = [&](int buf, int kt) {
    const size_t ko = (size_t)kt * 32;
    gload_lds16(aptr0 + ko, &As[buf][ldsOfsA0]);
    gload_lds16(aptr1 + ko, &As[buf][ldsOfsA1]);
    gload_lds16(bptr0 + ko, &Bs[buf][ldsOfsA0]);
    gload_lds16(bptr1 + ko, &Bs[buf][ldsOfsA1]);
  };

  stage(0, 0);
  if (nkt > 1) stage(1, 1);

  const int fr = lane & 15;
  const int s0 = (((lane >> 4) ^ ((fr >> 1) & 3)) << 3);

  int cur = 0;
  for (int kt = 0; kt < nkt; ++kt) {
    int nxt = cur + 2;
    if (nxt >= 3) nxt -= 3;
    if (kt + 2 < nkt) {
      stage(nxt, kt + 2);
      asm volatile("s_waitcnt vmcnt(8)" ::: "memory");
    } else if (kt + 1 < nkt) {
      asm volatile("s_waitcnt vmcnt(4)" ::: "memory");
    } else {
      asm volatile("s_waitcnt vmcnt(0)" ::: "memory");
    }
    __builtin_amdgcn_s_barrier();

    bf16x8 af[4], bfr[4];
#pragma unroll
    for (int m = 0; m < 4; ++m)
      af[m] = *(const bf16x8*)&As[cur][(wr * 64 + m * 16 + fr) * 32 + s0];
#pragma unroll
    for (int n = 0; n < 4; ++n)
      bfr[n] = *(const bf16x8*)&Bs[cur][(wc * 64 + n * 16 + fr) * 32 + s0];
#pragma unroll
    for (int m = 0; m < 4; ++m)
#pragma unroll
      for (int n = 0; n < 4; ++n)
        acc[m][n] = __builtin_amdgcn_mfma_f32_16x16x32_bf16(af[m], bfr[n], acc[m][n], 0, 0, 0);

    __builtin_amdgcn_s_barrier();
    cur += 1;
    if (cur >= 3) cur -= 3;
  }

  const int colBase = nblk * 128 + wc * 64 + (lane & 15);
  const int rowBase = mblk * 128 + wr * 64 + ((lane >> 4) << 2);
#pragma unroll
  for (int n = 0; n < 4; ++n) {
    const int c = colBase + n * 16;
    const float bv = bias[c];
#pragma unroll
    for (int m = 0; m < 4; ++m) {
#pragma unroll
      for (int j = 0; j < 4; ++j) {
        const int r = rowBase + m * 16 + j;
        Cbase[(size_t)r * N + c] = acc[m][n][j] + bv;
      }
    }
  }
}

// ---------------- 256x128 BK=32 expert GEMM1 ∥ W2/Wout transposes, 8 waves -------
// grid dim3(32,16,25): z<8 -> GEMM1 expert e=z; z in [8,25) -> transpose tiles
// (512-thread body): linear [0,8192) W2, [8192,8448) Wout.
__global__ __launch_bounds__(512, 4) void k_gemm1_t(
    const bf16_t* __restrict__ Abase, const bf16_t* __restrict__ Bbase,
    const float* __restrict__ biasBase, bf16_t* __restrict__ Cbase,
    int N, int K,
    const int* __restrict__ cnt, const int* __restrict__ listBase,
    const float* __restrict__ W2, const float* __restrict__ W_out,
    bf16_t* __restrict__ Wt2, bf16_t* __restrict__ WtOut) {
  __shared__ bf16_t As[3][256 * 32];
  __shared__ bf16_t Bs[3][128 * 32];

  if (blockIdx.z >= 8) {
    const int t6 = (blockIdx.z - 8) * 512 + blockIdx.y * 32 + blockIdx.x;
    if (t6 < 8192) {
      const int e = t6 >> 10, tt = t6 & 1023;
      transpose_tile512(W2 + (size_t)e * DMOE * DH, Wt2 + (size_t)e * DMOE * DH,
                        DMOE, DH, tt & 15, tt >> 4, As);
    } else if (t6 < 8448) {
      const int tt = t6 - 8192;
      transpose_tile512(W_out, WtOut, DH, DH, tt & 15, tt >> 4, As);
    }
    return;
  }

  const int e = blockIdx.z;
  const int mblk = blockIdx.y, nblk = blockIdx.x;
  const int Mloc = cnt[e];
  if (mblk * 256 >= Mloc) return;
  int rowOff = 0;
  for (int i = 0; i < NEXP; ++i) rowOff += (i < e) ? cnt[i] : 0;
  const bf16_t* B = Bbase + (size_t)e * N * K;
  const float* bias = biasBase + (size_t)e * N;
  const int* myList = listBase + e * NTOK;

  const int tid = threadIdx.x;
  const int lane = tid & 63;
  const int wid = tid >> 6;
  const int wr = wid >> 1, wc = wid & 1;

  const int subr = lane >> 2;
  const int skcol = ((lane & 3) ^ ((lane >> 3) & 3)) * 8;

  uint32_t aofs[2];
#pragma unroll
  for (int l = 0; l < 2; ++l) {
    int ar = mblk * 256 + (wid * 2 + l) * 16 + subr;
    if (ar > Mloc - 1) ar = Mloc - 1;
    aofs[l] = (uint32_t)(myList[ar] >> 1) * (uint32_t)K + skcol;
  }
  const uint32_t bofs = (uint32_t)(nblk * 128 + wid * 16 + subr) * (uint32_t)K + skcol;

  f32x4 acc[4][4] = {};
  const int nkt = K >> 5;

  auto stage = [&](int buf, int kt) {
    const uint32_t ko = (uint32_t)kt * 32;
    gload_lds16(Abase + aofs[0] + ko, &As[buf][(wid * 2 + 0) * 512]);
    gload_lds16(Abase + aofs[1] + ko, &As[buf][(wid * 2 + 1) * 512]);
    gload_lds16(B + bofs + ko, &Bs[buf][wid * 512]);
  };

  stage(0, 0);
  if (nkt > 1) stage(1, 1);

  const int fr = lane & 15;
  const int s0 = (((lane >> 4) ^ ((fr >> 1) & 3)) << 3);

  int cur = 0;
  for (int kt = 0; kt < nkt; ++kt) {
    int nxt = cur + 2;
    if (nxt >= 3) nxt -= 3;
    if (kt + 2 < nkt) {
      stage(nxt, kt + 2);
      asm volatile("s_waitcnt vmcnt(6)" ::: "memory");
    } else if (kt + 1 < nkt) {
      asm volatile("s_waitcnt vmcnt(3)" ::: "memory");
    } else {
      asm volatile("s_waitcnt vmcnt(0)" ::: "memory");
    }
    __builtin_amdgcn_s_barrier();

    bf16x8 af[4], bfr[4];
#pragma unroll
    for (int m = 0; m < 4; ++m)
      af[m] = *(const bf16x8*)&As[cur][(wr * 64 + m * 16 + fr) * 32 + s0];
#pragma unroll
    for (int n = 0; n < 4; ++n)
      bfr[n] = *(const bf16x8*)&Bs[cur][(wc * 64 + n * 16 + fr) * 32 + s0];
#pragma unroll
    for (int m = 0; m < 4; ++m)
#pragma unroll
      for (int n = 0; n < 4; ++n)
        acc[m][n] = __builtin_amdgcn_mfma_f32_16x16x32_bf16(af[m], bfr[n], acc[m][n], 0, 0, 0);

    __builtin_amdgcn_s_barrier();
    cur += 1;
    if (cur >= 3) cur -= 3;
  }

  const int colBase = nblk * 128 + wc * 64 + (lane & 15);
  const int rowBase = mblk * 256 + wr * 64 + ((lane >> 4) << 2);
#pragma unroll
  for (int n = 0; n < 4; ++n) {
    const int c = colBase + n * 16;
    const float bv = bias[c];
#pragma unroll
    for (int m = 0; m < 4; ++m) {
#pragma unroll
      for (int j = 0; j < 4; ++j) {
        const int r = rowBase + m * 16 + j;
        if (r < Mloc) {
          Cbase[(size_t)(rowOff + r) * N + c] = (bf16_t)fmaxf(acc[m][n][j] + bv, 0.0f);
        }
      }
    }
  }
}

// ---------------- 128x128 BK=32 expert GEMM2, 4 waves (R15-proven) ----
__global__ __launch_bounds__(256, 3) void k_gemm_e2(
    const bf16_t* __restrict__ Abase, const bf16_t* __restrict__ Bbase,
    const float* __restrict__ biasBase, bf16_t* __restrict__ Cbase,
    int N, int K,
    const int* __restrict__ cnt, const int* __restrict__ listBase,
    const float* __restrict__ wlistBase) {
  const int e = blockIdx.z;
  const int mblk = blockIdx.y, nblk = blockIdx.x;
  const int Mloc = cnt[e];
  if (mblk * 128 >= Mloc) return;
  int rowOff = 0;
  for (int i = 0; i < NEXP; ++i) rowOff += (i < e) ? cnt[i] : 0;
  const bf16_t* B = Bbase + (size_t)e * N * K;
  const float* bias = biasBase + (size_t)e * N;
  const int* myList = listBase + e * NTOK;
  const float* myW = wlistBase + e * NTOK;
  const bf16_t* A = Abase + (size_t)rowOff * K;

  __shared__ bf16_t As[3][128 * 32];
  __shared__ bf16_t Bs[3][128 * 32];

  const int tid = threadIdx.x;
  const int lane = tid & 63;
  const int wid = tid >> 6;
  const int wr = wid >> 1, wc = wid & 1;

  const int srow0 = wid * 32 + (lane >> 2);
  const int srow1 = srow0 + 16;
  const int skcol = ((lane & 3) ^ ((lane >> 3) & 3)) * 8;

  int ar0 = mblk * 128 + srow0;
  int ar1 = mblk * 128 + srow1;
  if (ar0 > Mloc - 1) ar0 = Mloc - 1;
  if (ar1 > Mloc - 1) ar1 = Mloc - 1;
  const bf16_t* aptr0 = A + (size_t)ar0 * K + skcol;
  const bf16_t* aptr1 = A + (size_t)ar1 * K + skcol;
  const bf16_t* bptr0 = B + (size_t)(nblk * 128 + srow0) * K + skcol;
  const bf16_t* bptr1 = B + (size_t)(nblk * 128 + srow1) * K + skcol;

  const int ldsOfsA0 = (wid * 32) * 32;
  const int ldsOfsA1 = (wid * 32 + 16) * 32;

  f32x4 acc[4][4] = {};
  const int nkt = K >> 5;

  auto stage = [&](int buf, int kt) {
    const size_t ko = (size_t)kt * 32;
    gload_lds16(aptr0 + ko, &As[buf][ldsOfsA0]);
    gload_lds16(aptr1 + ko, &As[buf][ldsOfsA1]);
    gload_lds16(bptr0 + ko, &Bs[buf][ldsOfsA0]);
    gload_lds16(bptr1 + ko, &Bs[buf][ldsOfsA1]);
  };

  stage(0, 0);
  if (nkt > 1) stage(1, 1);

  const int fr = lane & 15;
  const int s0 = (((lane >> 4) ^ ((fr >> 1) & 3)) << 3);

  int cur = 0;
  for (int kt = 0; kt < nkt; ++kt) {
    int nxt = cur + 2;
    if (nxt >= 3) nxt -= 3;
    if (kt + 2 < nkt) {
      stage(nxt, kt + 2);
      asm volatile("s_waitcnt vmcnt(8)" ::: "memory");
    } else if (kt + 1 < nkt) {
      asm volatile("s_waitcnt vmcnt(4)" ::: "memory");
    } else {
      asm volatile("s_waitcnt vmcnt(0)" ::: "memory");
    }
    __builtin_amdgcn_s_barrier();

    bf16x8 af[4], bfr[4];
#pragma unroll
    for (int m = 0; m < 4; ++m)
      af[m] = *(const bf16x8*)&As[cur][(wr * 64 + m * 16 + fr) * 32 + s0];
#pragma unroll
    for (int n = 0; n < 4; ++n)
      bfr[n] = *(const bf16x8*)&Bs[cur][(wc * 64 + n * 16 + fr) * 32 + s0];
#pragma unroll
    for (int m = 0; m < 4; ++m)
#pragma unroll
      for (int n = 0; n < 4; ++n)
        acc[m][n] = __builtin_amdgcn_mfma_f32_16x16x32_bf16(af[m], bfr[n], acc[m][n], 0, 0, 0);

    __builtin_amdgcn_s_barrier();
    cur += 1;
    if (cur >= 3) cur -= 3;
  }

  const int colBase = nblk * 128 + wc * 64 + (lane & 15);
  const int rowBase = mblk * 128 + wr * 64 + ((lane >> 4) << 2);
#pragma unroll
  for (int n = 0; n < 4; ++n) {
    const int c = colBase + n * 16;
    const float bv = bias[c];
#pragma unroll
    for (int m = 0; m < 4; ++m) {
#pragma unroll
      for (int j = 0; j < 4; ++j) {
        const int r = rowBase + m * 16 + j;
        if (r < Mloc) {
          const int entry = myList[r];
          const float w = myW[r];
          Cbase[(size_t)entry * DH + c] = (bf16_t)((acc[m][n][j] + bv) * w);
        }
      }
    }
  }
}

// ---------------- launch ----------------

extern "C" void kernel_launch(void* const* d_in, const int* in_sizes, int n_in,
                              void* d_out, int out_size, void* d_ws, size_t ws_size,
                              hipStream_t stream) {
  const float* x      = (const float*)d_in[0];
  const float* W_in   = (const float*)d_in[1];
  const float* b_in   = (const float*)d_in[2];
  const float* W_gate = (const float*)d_in[3];
  const float* b_gate = (const float*)d_in[4];
  const float* W1     = (const float*)d_in[5];
  const float* b1     = (const float*)d_in[6];
  const float* W2     = (const float*)d_in[7];
  const float* b2     = (const float*)d_in[8];
  const float* W_out  = (const float*)d_in[9];
  const float* b_out  = (const float*)d_in[10];

  char* ws = (char*)d_ws;
  size_t off = 0;
  auto alloc = [&](size_t bytes) -> void* {
    void* p = ws + off;
    off += (bytes + 255) & ~(size_t)255;
    return p;
  };

  bf16_t* WtIn  = (bf16_t*)alloc((size_t)DH * DIN * 2);
  bf16_t* Wt1   = (bf16_t*)alloc((size_t)NEXP * DMOE * DH * 2);
  bf16_t* Wt2   = (bf16_t*)alloc((size_t)NEXP * DH * DMOE * 2);
  bf16_t* WtOut = (bf16_t*)alloc((size_t)DH * DH * 2);
  bf16_t* xbf   = (bf16_t*)alloc((size_t)NTOK * DIN * 2);
  bf16_t* hbf   = (bf16_t*)alloc((size_t)NTOK * DH * 2);
  bf16_t* mid   = (bf16_t*)alloc((size_t)2 * NTOK * DMOE * 2);
  bf16_t* eoutb = (bf16_t*)alloc((size_t)2 * NTOK * DH * 2);
  bf16_t* moebf = (bf16_t*)alloc((size_t)NTOK * DH * 2);
  double* G     = (double*)alloc((size_t)DIN * 8 * 8);
  double* cvec  = (double*)alloc(8 * 8);
  int*    cnt   = (int*)alloc(NEXP * 4);
  int*    list  = (int*)alloc((size_t)NEXP * NTOK * 4);
  float*  wlist = (float*)alloc((size_t)NEXP * NTOK * 4);

  // small prep: WtIn transpose + x cvt + fp64 gate-prep (cnt zeroed)
  k_prep_small<<<4416, 256, 0, stream>>>(W_in, x, W_gate, b_in, b_gate,
                                         WtIn, xbf, G, cvec, cnt);

  // MEGA: GEMM0 (z=0) ∥ gating (z=1..4) ∥ W1 transpose (z=5..36)
  k_mega<<<dim3(DH / 128, NTOK / 128, 37), 256, 0, stream>>>(
      xbf, WtIn, b_in, hbf, x, G, cvec, cnt, list, wlist, W1, Wt1);

  // GEMM1 (z=0..7) ∥ W2/Wout transposes (z=8..24)
  k_gemm1_t<<<dim3(DMOE / 128, NTOK / 256, 25), 512, 0, stream>>>(
      hbf, Wt1, b1, mid, DMOE, DH, cnt, list, W2, W_out, Wt2, WtOut);

  // eout[entry] = bf16((mid @ W2[e] + b2[e]) * route_w)  (128^2, best-measured)
  k_gemm_e2<<<dim3(DH / 128, NTOK / 128, NEXP), 256, 0, stream>>>(
      mid, Wt2, b2, eoutb, DH, DMOE, cnt, list, wlist);
  k_combine<<<NTOK * DH / 4 / 256, 256, 0, stream>>>(eoutb, moebf);
  // out = moe @ W_out + b_out (fp32 out)
  k_gemm_out<<<dim3(DH / 128, NTOK / 128, 1), 256, 0, stream>>>(
      moebf, WtOut, b_out, (float*)d_out, NTOK, DH, DH);
}